// Round 1
// baseline (1019.890 us; speedup 1.0000x reference)
//
#include <hip/hip_runtime.h>
#include <stdint.h>

typedef unsigned short u16;
typedef unsigned int   u32;

// N = 160000, K = 16, C_IN = 64, C1 = 32, C_MID = 16, C2 = 64, C_OUT = 128
// Inputs: float32 (runtime probe retained as insurance). Outputs: float32.

__device__ __forceinline__ float bf2f(u16 h) {
  return __uint_as_float(((u32)h) << 16);
}
__device__ __forceinline__ float lrelu(float x) { return x > 0.f ? x : 0.1f * x; }

__device__ __forceinline__ float ldf(const void* p, size_t i, bool bf) {
  return bf ? bf2f(((const u16*)p)[i]) : ((const float*)p)[i];
}
__device__ __forceinline__ bool probe_bf16(const void* g) {
  return ((*(const u32*)g) & 0xFFFFu) == 0x3F80u;
}

// ---------------------------------------------------------------------------
// K1: feats_x = lrelu(feats @ (W_u1 * g) + b)   [N,64] -> [N,32], f32 out
// ---------------------------------------------------------------------------
__global__ __launch_bounds__(256) void k1_unary(
    const void* __restrict__ feats, const void* __restrict__ W,
    const void* __restrict__ g, const void* __restrict__ b,
    float* __restrict__ fx, int Npts)
{
  __shared__ float sW[64 * 32];
  __shared__ float sb[32];
  __shared__ float sf[8][64];
  bool bf = probe_bf16(g);
  int tid = threadIdx.x;
  for (int e = tid; e < 2048; e += 256) sW[e] = ldf(W, e, bf) * ldf(g, e & 31, bf);
  if (tid < 32) sb[tid] = ldf(b, tid, bf);
  int n0 = blockIdx.x * 8;
  for (int e = tid; e < 512; e += 256) {
    int p = e >> 6, i = e & 63;
    int n = n0 + p;
    sf[p][i] = (n < Npts) ? ldf(feats, (size_t)n * 64 + i, bf) : 0.f;
  }
  __syncthreads();
  int p = tid >> 5, c = tid & 31;
  int n = n0 + p;
  if (n < Npts) {
    float acc = sb[c];
#pragma unroll
    for (int i = 0; i < 64; ++i) acc += sf[p][i] * sW[i * 32 + c];
    fx[(size_t)n * 32 + c] = lrelu(acc);
  }
}

// ---------------------------------------------------------------------------
// K2: per point (one wave each, 4 waves/block), chunk [n0,n1):
//   localized_xyz -> out1 (f32) and LDS; WeightNet -> w[16,16];
//   gather feats_x ; einsum -> nf f32 (chunk-local)
// ---------------------------------------------------------------------------
__global__ __launch_bounds__(256) void k2_point(
    const void* __restrict__ xyz, const int* __restrict__ nei,
    const float* __restrict__ fx,
    const void* __restrict__ W0, const void* __restrict__ g0, const void* __restrict__ b0,
    const void* __restrict__ W1, const void* __restrict__ g1, const void* __restrict__ b1,
    const void* __restrict__ W2, const void* __restrict__ g2, const void* __restrict__ b2,
    float* __restrict__ nf, float* __restrict__ locout, int n0, int n1)
{
  __shared__ float sW0[24], sB0[8], sW1[64], sB1[8], sW2[128], sB2[16];
  __shared__ int   sIdx[4][16];
  __shared__ float sLoc[4][48];
  __shared__ float sHa[4][128];
  __shared__ float sHb[4][128];
  alignas(16) __shared__ float sP[4][256];
  alignas(16) __shared__ float sGF[4][512];

  bool bf = probe_bf16(g0);
  int tid = threadIdx.x;
  if (tid < 24) sW0[tid] = ldf(W0, tid, bf) * ldf(g0, tid & 7, bf);
  else if (tid < 32) sB0[tid - 24] = ldf(b0, tid - 24, bf);
  else if (tid < 96) sW1[tid - 32] = ldf(W1, tid - 32, bf) * ldf(g1, (tid - 32) & 7, bf);
  else if (tid < 104) sB1[tid - 96] = ldf(b1, tid - 96, bf);
  else if (tid < 232) sW2[tid - 104] = ldf(W2, tid - 104, bf) * ldf(g2, (tid - 104) & 15, bf);
  else if (tid < 248) sB2[tid - 232] = ldf(b2, tid - 232, bf);

  int w = tid >> 6, lane = tid & 63;
  int n = n0 + blockIdx.x * 4 + w;
  bool valid = n < n1;

  if (lane < 16) sIdx[w][lane] = valid ? nei[(size_t)n * 16 + lane] : 0;
  __syncthreads();

  if (lane < 48) {
    int k = lane / 3, d = lane - k * 3;
    float v = 0.f;
    if (valid) {
      int m = sIdx[w][k];
      v = ldf(xyz, (size_t)m * 3 + d, bf) - ldf(xyz, (size_t)n * 3 + d, bf);
      locout[(size_t)n * 48 + lane] = v;
    }
    sLoc[w][lane] = v;
  }
  __syncthreads();

#pragma unroll
  for (int r = 0; r < 2; ++r) {
    int o = lane + r * 64;
    int k = o >> 3, j = o & 7;
    float a = sB0[j];
#pragma unroll
    for (int d = 0; d < 3; ++d) a += sLoc[w][k * 3 + d] * sW0[d * 8 + j];
    sHa[w][o] = fmaxf(a, 0.f);
  }
  __syncthreads();
#pragma unroll
  for (int r = 0; r < 2; ++r) {
    int o = lane + r * 64;
    int k = o >> 3, j = o & 7;
    float a = sB1[j];
#pragma unroll
    for (int d = 0; d < 8; ++d) a += sHa[w][k * 8 + d] * sW1[d * 8 + j];
    sHb[w][o] = fmaxf(a, 0.f);
  }
  __syncthreads();
#pragma unroll
  for (int r = 0; r < 4; ++r) {
    int o = lane + r * 64;
    int k = o >> 4, j = o & 15;
    float a = sB2[j];
#pragma unroll
    for (int d = 0; d < 8; ++d) a += sHb[w][k * 8 + d] * sW2[d * 16 + j];
    sP[w][o] = fmaxf(a, 0.f);
  }

  {
    int e0 = lane * 8;
    int k = e0 >> 5, c0 = e0 & 31;
    float4 v0 = make_float4(0.f, 0.f, 0.f, 0.f), v1 = v0;
    if (valid) {
      int m = sIdx[w][k];
      const float4* src = reinterpret_cast<const float4*>(fx + (size_t)m * 32 + c0);
      v0 = src[0]; v1 = src[1];
    }
    float4* dst = reinterpret_cast<float4*>(&sGF[w][e0]);
    dst[0] = v0; dst[1] = v1;
  }
  __syncthreads();

  {
    int c = lane >> 1, mb = (lane & 1) * 8;
    float acc[8] = {0.f, 0.f, 0.f, 0.f, 0.f, 0.f, 0.f, 0.f};
#pragma unroll
    for (int k = 0; k < 16; ++k) {
      float f = sGF[w][k * 32 + c];
      const float4* pw = reinterpret_cast<const float4*>(&sP[w][k * 16 + mb]);
      float4 w0 = pw[0], w1 = pw[1];
      acc[0] += f * w0.x; acc[1] += f * w0.y; acc[2] += f * w0.z; acc[3] += f * w0.w;
      acc[4] += f * w1.x; acc[5] += f * w1.y; acc[6] += f * w1.z; acc[7] += f * w1.w;
    }
    if (valid) {
      float4* dst = reinterpret_cast<float4*>(nf + (size_t)(n - n0) * 512 + (c * 16 + mb));
      dst[0] = make_float4(acc[0], acc[1], acc[2], acc[3]);
      dst[1] = make_float4(acc[4], acc[5], acc[6], acc[7]);
    }
  }
}

// ---------------------------------------------------------------------------
// K3: tiled GEMM  h[cnt,64] = relu(nf[cnt,512] @ (W_lin*g) + b)
// BM=128 BN=64 BK=32, 128 thr, 8x8 acc/thread.
// A transposed in LDS (stride 132: 2-way write aliasing = free).
// B staged column-per-thread (write bank = (4q+lane)%32 -> 2-way = free).
// Inner loop: 4 ds_read_b128 per 64 FMAs -> VALU-bound, not LDS-bound.
// ---------------------------------------------------------------------------
__global__ __launch_bounds__(128) void k3_gemm(
    const float* __restrict__ nf, const void* __restrict__ WL,
    const void* __restrict__ gl, const void* __restrict__ bl,
    float* __restrict__ h, int cnt)
{
  __shared__ float sA[32][132];   // [k][m]
  __shared__ float sB[32][68];    // [k][j], g-folded
  bool bf = probe_bf16(gl);
  int t = threadIdx.x;
  int tx = t & 7;        // cols tx*8 .. tx*8+7
  int ty = t >> 3;       // rows ty*8 .. ty*8+7   (0..15)
  int m0 = blockIdx.x * 128;

  float acc[8][8] = {{0.f}};

  int arow = t;                // A staging: this thread's output row
  int bj   = t & 63;           // B staging: this thread's column
  int bk0  = (t >> 6) * 16;    // B staging: k-half (0 or 16)
  float gj = ldf(gl, bj, bf);

  for (int kb = 0; kb < 512; kb += 32) {
    // stage A (transposed): thread t loads nf[m0+t][kb..kb+32)
    {
      int m = m0 + arow;
      if (m < cnt) {
        const float4* src = reinterpret_cast<const float4*>(nf + (size_t)m * 512 + kb);
#pragma unroll
        for (int r = 0; r < 8; ++r) {
          float4 x = src[r];
          sA[r * 4 + 0][arow] = x.x;
          sA[r * 4 + 1][arow] = x.y;
          sA[r * 4 + 2][arow] = x.z;
          sA[r * 4 + 3][arow] = x.w;
        }
      } else {
#pragma unroll
        for (int r = 0; r < 32; ++r) sA[r][arow] = 0.f;
      }
    }
    // stage B: thread owns column bj, walks 16 k's (coalesced global per q)
    {
#pragma unroll
      for (int q = 0; q < 16; ++q) {
        int kk = bk0 + q;
        sB[kk][bj] = ldf(WL, (size_t)(kb + kk) * 64 + bj, bf) * gj;
      }
    }
    __syncthreads();
#pragma unroll
    for (int kk = 0; kk < 32; ++kk) {
      float4 a0 = *reinterpret_cast<const float4*>(&sA[kk][ty * 8]);
      float4 a1 = *reinterpret_cast<const float4*>(&sA[kk][ty * 8 + 4]);
      float4 b0 = *reinterpret_cast<const float4*>(&sB[kk][tx * 8]);
      float4 b1 = *reinterpret_cast<const float4*>(&sB[kk][tx * 8 + 4]);
      float av[8] = {a0.x, a0.y, a0.z, a0.w, a1.x, a1.y, a1.z, a1.w};
      float bv[8] = {b0.x, b0.y, b0.z, b0.w, b1.x, b1.y, b1.z, b1.w};
#pragma unroll
      for (int i = 0; i < 8; ++i)
#pragma unroll
        for (int j = 0; j < 8; ++j) acc[i][j] += av[i] * bv[j];
    }
    __syncthreads();
  }

  float bias[8];
#pragma unroll
  for (int j = 0; j < 8; ++j) bias[j] = ldf(bl, tx * 8 + j, bf);

#pragma unroll
  for (int i = 0; i < 8; ++i) {
    int m = m0 + ty * 8 + i;
    if (m < cnt) {
      float4 o0, o1;
      float* p0 = &o0.x; float* p1 = &o1.x;
#pragma unroll
      for (int j = 0; j < 4; ++j) {
        p0[j] = fmaxf(acc[i][j]     + bias[j],     0.f);
        p1[j] = fmaxf(acc[i][4 + j] + bias[4 + j], 0.f);
      }
      *reinterpret_cast<float4*>(h + (size_t)m * 64 + tx * 8)     = o0;
      *reinterpret_cast<float4*>(h + (size_t)m * 64 + tx * 8 + 4) = o1;
    }
  }
}

// ---------------------------------------------------------------------------
// K4: tiled GEMM  out[cnt,128] = lrelu([h|feats] @ [[Wu2*g];[Wsc*g]] + bu2+bsc)
// BM=128 BN=128 BK=32, 256 thr, 8x8 acc/thread (cols tx*4 and 64+tx*4:
// stride-4-dword reads are 2-way = free at LDS stride 132).
// Conflict-free column/row-per-thread staging as in K3.
// ---------------------------------------------------------------------------
__global__ __launch_bounds__(256) void k4_gemm(
    const float* __restrict__ h, const void* __restrict__ feats,
    const void* __restrict__ Wu2, const void* __restrict__ gu2, const void* __restrict__ bu2,
    const void* __restrict__ Wsc, const void* __restrict__ gsc, const void* __restrict__ bsc,
    float* __restrict__ out, int n0c, int cnt)
{
  __shared__ float sA[32][132];    // [k][m]
  __shared__ float sB[32][132];    // [k][o], g-folded
  bool bf = probe_bf16(gu2);
  int t = threadIdx.x;
  int tx = t & 15, ty = t >> 4;    // cols tx*4 & 64+tx*4 ; rows ty*8..+7
  int m0 = blockIdx.x * 128;

  float acc[8][8] = {{0.f}};

  int arow = t & 127;              // A staging row
  int ak0  = (t >> 7) * 16;        // A staging k-half
  int bo   = t & 127;              // B staging column
  int bk0  = (t >> 7) * 16;        // B staging k-half

  for (int kb = 0; kb < 128; kb += 32) {
    // stage A: k<64 from h (chunk-local f32), k>=64 from feats (absolute)
    {
      int m = m0 + arow;
      float v[16];
      if (m < cnt) {
        if (kb < 64) {
          const float4* src = reinterpret_cast<const float4*>(h + (size_t)m * 64 + kb + ak0);
#pragma unroll
          for (int r = 0; r < 4; ++r) {
            float4 x = src[r];
            v[4 * r] = x.x; v[4 * r + 1] = x.y; v[4 * r + 2] = x.z; v[4 * r + 3] = x.w;
          }
        } else {
#pragma unroll
          for (int q = 0; q < 16; ++q)
            v[q] = ldf(feats, (size_t)(n0c + m) * 64 + (kb - 64) + ak0 + q, bf);
        }
      } else {
#pragma unroll
        for (int q = 0; q < 16; ++q) v[q] = 0.f;
      }
#pragma unroll
      for (int q = 0; q < 16; ++q) sA[ak0 + q][arow] = v[q];
    }
    // stage B: thread owns column bo, walks 16 k's; k-range stays on one
    // side of the 64-boundary (kb mult of 32, bk0 in {0,16})
    {
      int kg0 = kb + bk0;
      const void* Wsel = (kg0 < 64) ? Wu2 : Wsc;
      const void* gsel = (kg0 < 64) ? gu2 : gsc;
      int kr0 = (kg0 < 64) ? kg0 : kg0 - 64;
      float go = ldf(gsel, bo, bf);
#pragma unroll
      for (int q = 0; q < 16; ++q)
        sB[bk0 + q][bo] = ldf(Wsel, (size_t)(kr0 + q) * 128 + bo, bf) * go;
    }
    __syncthreads();
#pragma unroll
    for (int kk = 0; kk < 32; ++kk) {
      float4 a0 = *reinterpret_cast<const float4*>(&sA[kk][ty * 8]);
      float4 a1 = *reinterpret_cast<const float4*>(&sA[kk][ty * 8 + 4]);
      float4 b0 = *reinterpret_cast<const float4*>(&sB[kk][tx * 4]);
      float4 b1 = *reinterpret_cast<const float4*>(&sB[kk][64 + tx * 4]);
      float av[8] = {a0.x, a0.y, a0.z, a0.w, a1.x, a1.y, a1.z, a1.w};
      float bv[8] = {b0.x, b0.y, b0.z, b0.w, b1.x, b1.y, b1.z, b1.w};
#pragma unroll
      for (int i = 0; i < 8; ++i)
#pragma unroll
        for (int j = 0; j < 8; ++j) acc[i][j] += av[i] * bv[j];
    }
    __syncthreads();
  }

  float bias0[4], bias1[4];
#pragma unroll
  for (int j = 0; j < 4; ++j) {
    int c0 = tx * 4 + j, c1 = 64 + tx * 4 + j;
    bias0[j] = ldf(bu2, c0, bf) + ldf(bsc, c0, bf);
    bias1[j] = ldf(bu2, c1, bf) + ldf(bsc, c1, bf);
  }

#pragma unroll
  for (int i = 0; i < 8; ++i) {
    int m = m0 + ty * 8 + i;
    if (m < cnt) {
      float4 o0v, o1v;
      float* p0 = &o0v.x; float* p1 = &o1v.x;
#pragma unroll
      for (int j = 0; j < 4; ++j) {
        p0[j] = lrelu(acc[i][j]     + bias0[j]);
        p1[j] = lrelu(acc[i][4 + j] + bias1[j]);
      }
      float* orow = out + (size_t)(n0c + m) * 128;
      *reinterpret_cast<float4*>(orow + tx * 4)      = o0v;
      *reinterpret_cast<float4*>(orow + 64 + tx * 4) = o1v;
    }
  }
}

extern "C" void kernel_launch(void* const* d_in, const int* in_sizes, int n_in,
                              void* d_out, int out_size, void* d_ws, size_t ws_size,
                              hipStream_t stream) {
  const void* xyz   = d_in[0];
  const void* feats = d_in[1];
  const int*  nei   = (const int*)d_in[2];
  const void* W_u1  = d_in[3];
  const void* g_u1  = d_in[4];
  const void* b_u1  = d_in[5];
  const void* W_wn0 = d_in[6];
  const void* g_wn0 = d_in[7];
  const void* b_wn0 = d_in[8];
  const void* W_wn1 = d_in[9];
  const void* g_wn1 = d_in[10];
  const void* b_wn1 = d_in[11];
  const void* W_wn2 = d_in[12];
  const void* g_wn2 = d_in[13];
  const void* b_wn2 = d_in[14];
  const void* W_lin = d_in[15];
  const void* g_lin = d_in[16];
  const void* b_lin = d_in[17];
  const void* W_u2  = d_in[18];
  const void* g_u2  = d_in[19];
  const void* b_u2  = d_in[20];
  const void* W_sc  = d_in[21];
  const void* g_sc  = d_in[22];
  const void* b_sc  = d_in[23];

  int Npts = in_sizes[0] / 3;

  float* out0 = (float*)d_out;                 // [N,128] f32
  float* out1 = out0 + (size_t)Npts * 128;     // [N,16,3] f32

  float* fx = (float*)d_ws;
  size_t fx_bytes = (size_t)Npts * 32 * 4;
  size_t avail = (ws_size > fx_bytes) ? (ws_size - fx_bytes) : 0;
  size_t per_pt = (size_t)(512 + 64) * 4;  // 2304 B/point
  long long cN = (long long)(avail / per_pt);
  if (cN < 1) cN = 1;
  if (cN > Npts) cN = Npts;
  int chunkN = (int)cN;

  float* nf = fx + (size_t)Npts * 32;
  float* hb = nf + (size_t)chunkN * 512;

  k1_unary<<<(Npts + 7) / 8, 256, 0, stream>>>(feats, W_u1, g_u1, b_u1, fx, Npts);

  for (int n0 = 0; n0 < Npts; n0 += chunkN) {
    int n1 = n0 + chunkN;
    if (n1 > Npts) n1 = Npts;
    int cnt = n1 - n0;
    k2_point<<<(cnt + 3) / 4, 256, 0, stream>>>(
        xyz, nei, fx,
        W_wn0, g_wn0, b_wn0, W_wn1, g_wn1, b_wn1, W_wn2, g_wn2, b_wn2,
        nf, out1, n0, n1);
    int gB = (cnt + 127) / 128;
    k3_gemm<<<gB, 128, 0, stream>>>(nf, W_lin, g_lin, b_lin, hb, cnt);
    k4_gemm<<<gB, 256, 0, stream>>>(hb, feats, W_u2, g_u2, b_u2,
                                    W_sc, g_sc, b_sc, out0, n0, cnt);
  }
}

// Round 2
// 603.942 us; speedup vs baseline: 1.6887x; 1.6887x over previous
//
#include <hip/hip_runtime.h>
#include <stdint.h>

typedef unsigned short u16;
typedef unsigned int   u32;

typedef __attribute__((ext_vector_type(8))) short bf16x8;
typedef __attribute__((ext_vector_type(4))) float f32x4;

// N = 160000, K = 16, C_IN = 64, C1 = 32, C_MID = 16, C2 = 64, C_OUT = 128
// Harness delivers bf16 inputs (probe fires; absmax 0.0625 with pure-f32 math).
// nf intermediate stored bf16 -> k3 runs on the matrix pipe.

__device__ __forceinline__ float bf2f(u16 h) {
  return __uint_as_float(((u32)h) << 16);
}
__device__ __forceinline__ float lrelu(float x) { return x > 0.f ? x : 0.1f * x; }

__device__ __forceinline__ float ldf(const void* p, size_t i, bool bf) {
  return bf ? bf2f(((const u16*)p)[i]) : ((const float*)p)[i];
}
__device__ __forceinline__ bool probe_bf16(const void* g) {
  return ((*(const u32*)g) & 0xFFFFu) == 0x3F80u;
}
__device__ __forceinline__ u16 f2bf(float x) {  // round-to-nearest-even
  u32 u = __float_as_uint(x);
  return (u16)((u + 0x7FFFu + ((u >> 16) & 1u)) >> 16);
}

// ---------------------------------------------------------------------------
// K1: feats_x = lrelu(feats @ (W_u1 * g) + b)   [N,64] -> [N,32], f32 out
// ---------------------------------------------------------------------------
__global__ __launch_bounds__(256) void k1_unary(
    const void* __restrict__ feats, const void* __restrict__ W,
    const void* __restrict__ g, const void* __restrict__ b,
    float* __restrict__ fx, int Npts)
{
  __shared__ float sW[64 * 32];
  __shared__ float sb[32];
  __shared__ float sf[8][64];
  bool bf = probe_bf16(g);
  int tid = threadIdx.x;
  for (int e = tid; e < 2048; e += 256) sW[e] = ldf(W, e, bf) * ldf(g, e & 31, bf);
  if (tid < 32) sb[tid] = ldf(b, tid, bf);
  int n0 = blockIdx.x * 8;
  for (int e = tid; e < 512; e += 256) {
    int p = e >> 6, i = e & 63;
    int n = n0 + p;
    sf[p][i] = (n < Npts) ? ldf(feats, (size_t)n * 64 + i, bf) : 0.f;
  }
  __syncthreads();
  int p = tid >> 5, c = tid & 31;
  int n = n0 + p;
  if (n < Npts) {
    float acc = sb[c];
#pragma unroll
    for (int i = 0; i < 64; ++i) acc += sf[p][i] * sW[i * 32 + c];
    fx[(size_t)n * 32 + c] = lrelu(acc);
  }
}

// ---------------------------------------------------------------------------
// K2: per point (one wave each, 4 waves/block), chunk [n0,n1):
//   localized_xyz -> out1 (f32) and LDS; WeightNet -> w[16,16];
//   gather feats_x ; einsum -> nf (bf16, chunk-local)
// ---------------------------------------------------------------------------
__global__ __launch_bounds__(256) void k2_point(
    const void* __restrict__ xyz, const int* __restrict__ nei,
    const float* __restrict__ fx,
    const void* __restrict__ W0, const void* __restrict__ g0, const void* __restrict__ b0,
    const void* __restrict__ W1, const void* __restrict__ g1, const void* __restrict__ b1,
    const void* __restrict__ W2, const void* __restrict__ g2, const void* __restrict__ b2,
    u16* __restrict__ nf16, float* __restrict__ locout, int n0, int n1)
{
  __shared__ float sW0[24], sB0[8], sW1[64], sB1[8], sW2[128], sB2[16];
  __shared__ int   sIdx[4][16];
  __shared__ float sLoc[4][48];
  __shared__ float sHa[4][128];
  __shared__ float sHb[4][128];
  alignas(16) __shared__ float sP[4][256];
  alignas(16) __shared__ float sGF[4][512];

  bool bf = probe_bf16(g0);
  int tid = threadIdx.x;
  if (tid < 24) sW0[tid] = ldf(W0, tid, bf) * ldf(g0, tid & 7, bf);
  else if (tid < 32) sB0[tid - 24] = ldf(b0, tid - 24, bf);
  else if (tid < 96) sW1[tid - 32] = ldf(W1, tid - 32, bf) * ldf(g1, (tid - 32) & 7, bf);
  else if (tid < 104) sB1[tid - 96] = ldf(b1, tid - 96, bf);
  else if (tid < 232) sW2[tid - 104] = ldf(W2, tid - 104, bf) * ldf(g2, (tid - 104) & 15, bf);
  else if (tid < 248) sB2[tid - 232] = ldf(b2, tid - 232, bf);

  int w = tid >> 6, lane = tid & 63;
  int n = n0 + blockIdx.x * 4 + w;
  bool valid = n < n1;

  if (lane < 16) sIdx[w][lane] = valid ? nei[(size_t)n * 16 + lane] : 0;
  __syncthreads();

  if (lane < 48) {
    int k = lane / 3, d = lane - k * 3;
    float v = 0.f;
    if (valid) {
      int m = sIdx[w][k];
      v = ldf(xyz, (size_t)m * 3 + d, bf) - ldf(xyz, (size_t)n * 3 + d, bf);
      locout[(size_t)n * 48 + lane] = v;
    }
    sLoc[w][lane] = v;
  }
  __syncthreads();

#pragma unroll
  for (int r = 0; r < 2; ++r) {
    int o = lane + r * 64;
    int k = o >> 3, j = o & 7;
    float a = sB0[j];
#pragma unroll
    for (int d = 0; d < 3; ++d) a += sLoc[w][k * 3 + d] * sW0[d * 8 + j];
    sHa[w][o] = fmaxf(a, 0.f);
  }
  __syncthreads();
#pragma unroll
  for (int r = 0; r < 2; ++r) {
    int o = lane + r * 64;
    int k = o >> 3, j = o & 7;
    float a = sB1[j];
#pragma unroll
    for (int d = 0; d < 8; ++d) a += sHa[w][k * 8 + d] * sW1[d * 8 + j];
    sHb[w][o] = fmaxf(a, 0.f);
  }
  __syncthreads();
#pragma unroll
  for (int r = 0; r < 4; ++r) {
    int o = lane + r * 64;
    int k = o >> 4, j = o & 15;
    float a = sB2[j];
#pragma unroll
    for (int d = 0; d < 8; ++d) a += sHb[w][k * 8 + d] * sW2[d * 16 + j];
    sP[w][o] = fmaxf(a, 0.f);
  }

  {
    int e0 = lane * 8;
    int k = e0 >> 5, c0 = e0 & 31;
    float4 v0 = make_float4(0.f, 0.f, 0.f, 0.f), v1 = v0;
    if (valid) {
      int m = sIdx[w][k];
      const float4* src = reinterpret_cast<const float4*>(fx + (size_t)m * 32 + c0);
      v0 = src[0]; v1 = src[1];
    }
    float4* dst = reinterpret_cast<float4*>(&sGF[w][e0]);
    dst[0] = v0; dst[1] = v1;
  }
  __syncthreads();

  {
    int c = lane >> 1, mb = (lane & 1) * 8;
    float acc[8] = {0.f, 0.f, 0.f, 0.f, 0.f, 0.f, 0.f, 0.f};
#pragma unroll
    for (int k = 0; k < 16; ++k) {
      float f = sGF[w][k * 32 + c];
      const float4* pw = reinterpret_cast<const float4*>(&sP[w][k * 16 + mb]);
      float4 w0 = pw[0], w1 = pw[1];
      acc[0] += f * w0.x; acc[1] += f * w0.y; acc[2] += f * w0.z; acc[3] += f * w0.w;
      acc[4] += f * w1.x; acc[5] += f * w1.y; acc[6] += f * w1.z; acc[7] += f * w1.w;
    }
    if (valid) {
      bf16x8 pk;
#pragma unroll
      for (int e = 0; e < 8; ++e) pk[e] = (short)f2bf(acc[e]);
      *reinterpret_cast<bf16x8*>(nf16 + (size_t)(n - n0) * 512 + (c * 16 + mb)) = pk;
    }
  }
}

// ---------------------------------------------------------------------------
// K3: MFMA bf16 GEMM  h[cnt,64] = relu(nf16[cnt,512] @ (W_lin*g) + b), f32 out
// 256 thr = 4 waves; tile BM=128 x BN=64; wave -> 32 rows x 64 cols
// (2 m-frags x 4 n-frags of 16x16, K-step 32 via mfma_f32_16x16x32_bf16).
// Full B (512x64 bf16, g-folded) staged once: Bs[col][k] 64KB.
// A staged per 64-k slab: As[row][k] 16KB. Both XOR-swizzled on 16B chunks
// (chunk ^= row&7) -> all ds accesses 2-way aliased = free.
// ---------------------------------------------------------------------------
__global__ __launch_bounds__(256) void k3_gemm(
    const u16* __restrict__ nf, const void* __restrict__ WL,
    const void* __restrict__ gl, const void* __restrict__ bl,
    float* __restrict__ h, int cnt)
{
  alignas(16) __shared__ u16 As[128 * 64];   // [row][kchunk swizzled]
  alignas(16) __shared__ u16 Bs[64 * 512];   // [col][kchunk swizzled]
  bool bf = probe_bf16(gl);
  int t = threadIdx.x;
  int lane = t & 63, w = t >> 6;
  int m0 = blockIdx.x * 128;

  // ---- stage all of B once (g-folded, bf16, swizzled) ----
  {
    int c = t & 63, kh = t >> 6;          // column, k-quarter
    float gc = ldf(gl, c, bf);
    int k0 = kh * 128;
#pragma unroll
    for (int q = 0; q < 16; ++q) {
      int kbase = k0 + q * 8;
      bf16x8 pk;
#pragma unroll
      for (int e = 0; e < 8; ++e)
        pk[e] = (short)f2bf(ldf(WL, (size_t)(kbase + e) * 64 + c, bf) * gc);
      int chunk = (kbase >> 3) ^ (c & 7);
      *reinterpret_cast<bf16x8*>(&Bs[c * 512 + chunk * 8]) = pk;
    }
  }

  f32x4 acc[2][4];
#pragma unroll
  for (int mi = 0; mi < 2; ++mi)
#pragma unroll
    for (int ni = 0; ni < 4; ++ni) acc[mi][ni] = (f32x4){0.f, 0.f, 0.f, 0.f};

  int mrow = t >> 1;            // staging row 0..127
  int half = t & 1;             // k-half of the 64-k slab

  for (int kb = 0; kb < 512; kb += 64) {
    __syncthreads();  // previous slab consumed (and Bs ready on first iter)
    // ---- stage A slab: rows m0..m0+127, k in [kb, kb+64) ----
    {
      int gm = m0 + mrow;
      if (gm >= cnt) gm = cnt - 1;        // clamp: safe reads, rows unused
      const u16* src = nf + (size_t)gm * 512 + kb + half * 32;
#pragma unroll
      for (int q = 0; q < 4; ++q) {
        bf16x8 v = *reinterpret_cast<const bf16x8*>(src + q * 8);
        int chunk = (half * 4 + q) ^ (mrow & 7);
        *reinterpret_cast<bf16x8*>(&As[mrow * 64 + chunk * 8]) = v;
      }
    }
    __syncthreads();
    // ---- compute: two K-steps of 32 ----
#pragma unroll
    for (int ks = 0; ks < 2; ++ks) {
      int qg = lane >> 4;                 // k-group 0..3
      bf16x8 a[2];
#pragma unroll
      for (int mi = 0; mi < 2; ++mi) {
        int row = w * 32 + mi * 16 + (lane & 15);
        int chunk = (ks * 4 + qg) ^ (row & 7);
        a[mi] = *reinterpret_cast<const bf16x8*>(&As[row * 64 + chunk * 8]);
      }
      bf16x8 bfr[4];
#pragma unroll
      for (int ni = 0; ni < 4; ++ni) {
        int col = ni * 16 + (lane & 15);
        int chunk = ((kb >> 3) + ks * 4 + qg) ^ (col & 7);
        bfr[ni] = *reinterpret_cast<const bf16x8*>(&Bs[col * 512 + chunk * 8]);
      }
#pragma unroll
      for (int mi = 0; mi < 2; ++mi)
#pragma unroll
        for (int ni = 0; ni < 4; ++ni)
          acc[mi][ni] = __builtin_amdgcn_mfma_f32_16x16x32_bf16(
              a[mi], bfr[ni], acc[mi][ni], 0, 0, 0);
    }
  }

  // ---- epilogue: C/D layout col=lane&15, row=(lane>>4)*4+reg ----
  int colb = lane & 15, rq = lane >> 4;
  float bias[4];
#pragma unroll
  for (int ni = 0; ni < 4; ++ni) bias[ni] = ldf(bl, ni * 16 + colb, bf);
#pragma unroll
  for (int mi = 0; mi < 2; ++mi) {
#pragma unroll
    for (int v = 0; v < 4; ++v) {
      int m = m0 + w * 32 + mi * 16 + rq * 4 + v;
      if (m < cnt) {
#pragma unroll
        for (int ni = 0; ni < 4; ++ni) {
          int j = ni * 16 + colb;
          h[(size_t)m * 64 + j] = fmaxf(acc[mi][ni][v] + bias[ni], 0.f);
        }
      }
    }
  }
}

// ---------------------------------------------------------------------------
// K4: tiled GEMM  out[cnt,128] = lrelu([h|feats] @ [[Wu2*g];[Wsc*g]] + bu2+bsc)
// BM=64 BN=128 BK=32, 256 thr, 4x8 acc/thread (round-0 proven version).
// ---------------------------------------------------------------------------
__global__ __launch_bounds__(256) void k4_gemm(
    const float* __restrict__ h, const void* __restrict__ feats,
    const void* __restrict__ Wu2, const void* __restrict__ gu2, const void* __restrict__ bu2,
    const void* __restrict__ Wsc, const void* __restrict__ gsc, const void* __restrict__ bsc,
    float* __restrict__ out, int n0c, int cnt)
{
  __shared__ float sA[32][68];    // [k][m]
  __shared__ float sB[32][132];   // [k][o], g-folded
  bool bf = probe_bf16(gu2);
  int t = threadIdx.x;
  int tx = t & 15, ty = t >> 4;
  int m0 = blockIdx.x * 64;

  float acc[4][8] = {{0.f}};

  for (int kb = 0; kb < 128; kb += 32) {
    // stage A: k<64 from h (chunk-local), k>=64 from feats (absolute)
    {
      int row = t >> 2, j0 = (t & 3) * 8;
      int m = m0 + row;
      float v[8];
      if (m < cnt) {
        if (kb < 64) {
          const float4* src = reinterpret_cast<const float4*>(h + (size_t)m * 64 + kb + j0);
          float4 x0 = src[0], x1 = src[1];
          v[0]=x0.x; v[1]=x0.y; v[2]=x0.z; v[3]=x0.w;
          v[4]=x1.x; v[5]=x1.y; v[6]=x1.z; v[7]=x1.w;
        } else {
#pragma unroll
          for (int q = 0; q < 8; ++q)
            v[q] = ldf(feats, (size_t)(n0c + m) * 64 + (kb - 64) + j0 + q, bf);
        }
      } else {
#pragma unroll
        for (int q = 0; q < 8; ++q) v[q] = 0.f;
      }
#pragma unroll
      for (int q = 0; q < 8; ++q) sA[j0 + q][row] = v[q];
    }
    // stage B
    {
      int kk = t >> 3, o0 = (t & 7) * 16;
      int kg = kb + kk;
      const void* Wsel = (kg < 64) ? Wu2 : Wsc;
      const void* gsel = (kg < 64) ? gu2 : gsc;
      int krow = (kg < 64) ? kg : (kg - 64);
#pragma unroll
      for (int q = 0; q < 16; ++q) {
        int o = o0 + q;
        sB[kk][o] = ldf(Wsel, (size_t)krow * 128 + o, bf) * ldf(gsel, o, bf);
      }
    }
    __syncthreads();
#pragma unroll
    for (int kk = 0; kk < 32; ++kk) {
      float4 a  = *reinterpret_cast<const float4*>(&sA[kk][ty * 4]);
      float4 b0 = *reinterpret_cast<const float4*>(&sB[kk][tx * 4]);
      float4 b1 = *reinterpret_cast<const float4*>(&sB[kk][64 + tx * 4]);
      float av[4] = {a.x, a.y, a.z, a.w};
      float bv[8] = {b0.x, b0.y, b0.z, b0.w, b1.x, b1.y, b1.z, b1.w};
#pragma unroll
      for (int i = 0; i < 4; ++i)
#pragma unroll
        for (int j = 0; j < 8; ++j) acc[i][j] += av[i] * bv[j];
    }
    __syncthreads();
  }

#pragma unroll
  for (int i = 0; i < 4; ++i) {
    int m = m0 + ty * 4 + i;
    if (m < cnt) {
      float4 o0v, o1v;
      float* p0 = &o0v.x; float* p1 = &o1v.x;
#pragma unroll
      for (int j = 0; j < 4; ++j) {
        int c0 = tx * 4 + j, c1 = 64 + tx * 4 + j;
        p0[j] = lrelu(acc[i][j]     + ldf(bu2, c0, bf) + ldf(bsc, c0, bf));
        p1[j] = lrelu(acc[i][4 + j] + ldf(bu2, c1, bf) + ldf(bsc, c1, bf));
      }
      float* orow = out + (size_t)(n0c + m) * 128;
      *reinterpret_cast<float4*>(orow + tx * 4)      = o0v;
      *reinterpret_cast<float4*>(orow + 64 + tx * 4) = o1v;
    }
  }
}

extern "C" void kernel_launch(void* const* d_in, const int* in_sizes, int n_in,
                              void* d_out, int out_size, void* d_ws, size_t ws_size,
                              hipStream_t stream) {
  const void* xyz   = d_in[0];
  const void* feats = d_in[1];
  const int*  nei   = (const int*)d_in[2];
  const void* W_u1  = d_in[3];
  const void* g_u1  = d_in[4];
  const void* b_u1  = d_in[5];
  const void* W_wn0 = d_in[6];
  const void* g_wn0 = d_in[7];
  const void* b_wn0 = d_in[8];
  const void* W_wn1 = d_in[9];
  const void* g_wn1 = d_in[10];
  const void* b_wn1 = d_in[11];
  const void* W_wn2 = d_in[12];
  const void* g_wn2 = d_in[13];
  const void* b_wn2 = d_in[14];
  const void* W_lin = d_in[15];
  const void* g_lin = d_in[16];
  const void* b_lin = d_in[17];
  const void* W_u2  = d_in[18];
  const void* g_u2  = d_in[19];
  const void* b_u2  = d_in[20];
  const void* W_sc  = d_in[21];
  const void* g_sc  = d_in[22];
  const void* b_sc  = d_in[23];

  int Npts = in_sizes[0] / 3;

  float* out0 = (float*)d_out;                 // [N,128] f32
  float* out1 = out0 + (size_t)Npts * 128;     // [N,16,3] f32

  float* fx = (float*)d_ws;                    // [N,32] f32
  size_t fx_bytes = (size_t)Npts * 32 * 4;
  size_t avail = (ws_size > fx_bytes) ? (ws_size - fx_bytes) : 0;
  size_t per_pt = (size_t)512 * 2 + (size_t)64 * 4;  // nf bf16 + h f32 = 1280 B/pt
  long long cN = (long long)(avail / per_pt);
  if (cN < 1) cN = 1;
  if (cN > Npts) cN = Npts;
  int chunkN = (int)cN;

  u16*   nf16 = (u16*)(fx + (size_t)Npts * 32);
  float* hb   = (float*)((char*)nf16 + (size_t)chunkN * 512 * 2);

  k1_unary<<<(Npts + 7) / 8, 256, 0, stream>>>(feats, W_u1, g_u1, b_u1, fx, Npts);

  for (int n0 = 0; n0 < Npts; n0 += chunkN) {
    int n1 = n0 + chunkN;
    if (n1 > Npts) n1 = Npts;
    int cnt = n1 - n0;
    k2_point<<<(cnt + 3) / 4, 256, 0, stream>>>(
        xyz, nei, fx,
        W_wn0, g_wn0, b_wn0, W_wn1, g_wn1, b_wn1, W_wn2, g_wn2, b_wn2,
        nf16, out1, n0, n1);
    k3_gemm<<<(cnt + 127) / 128, 256, 0, stream>>>(nf16, W_lin, g_lin, b_lin, hb, cnt);
    k4_gemm<<<(cnt + 63) / 64, 256, 0, stream>>>(hb, feats, W_u2, g_u2, b_u2,
                                                 W_sc, g_sc, b_sc, out0, n0, cnt);
  }
}

// Round 3
// 457.814 us; speedup vs baseline: 2.2277x; 1.3192x over previous
//
#include <hip/hip_runtime.h>
#include <stdint.h>

typedef unsigned short u16;
typedef unsigned int   u32;

typedef __attribute__((ext_vector_type(8))) short bf16x8;
typedef __attribute__((ext_vector_type(4))) float f32x4;

// N = 160000, K = 16, C_IN = 64, C1 = 32, C_MID = 16, C2 = 64, C_OUT = 128
// Harness delivers bf16 inputs (probe fires). nf and h intermediates stored
// bf16 -> k3 and k4 both run on the matrix pipe.

__device__ __forceinline__ float bf2f(u16 h) {
  return __uint_as_float(((u32)h) << 16);
}
__device__ __forceinline__ float lrelu(float x) { return x > 0.f ? x : 0.1f * x; }

__device__ __forceinline__ float ldf(const void* p, size_t i, bool bf) {
  return bf ? bf2f(((const u16*)p)[i]) : ((const float*)p)[i];
}
__device__ __forceinline__ bool probe_bf16(const void* g) {
  return ((*(const u32*)g) & 0xFFFFu) == 0x3F80u;
}
__device__ __forceinline__ u16 f2bf(float x) {  // round-to-nearest-even
  u32 u = __float_as_uint(x);
  return (u16)((u + 0x7FFFu + ((u >> 16) & 1u)) >> 16);
}

// ---------------------------------------------------------------------------
// K1: feats_x = lrelu(feats @ (W_u1 * g) + b)   [N,64] -> [N,32], f32 out
// ---------------------------------------------------------------------------
__global__ __launch_bounds__(256) void k1_unary(
    const void* __restrict__ feats, const void* __restrict__ W,
    const void* __restrict__ g, const void* __restrict__ b,
    float* __restrict__ fx, int Npts)
{
  __shared__ float sW[64 * 32];
  __shared__ float sb[32];
  __shared__ float sf[8][64];
  bool bf = probe_bf16(g);
  int tid = threadIdx.x;
  for (int e = tid; e < 2048; e += 256) sW[e] = ldf(W, e, bf) * ldf(g, e & 31, bf);
  if (tid < 32) sb[tid] = ldf(b, tid, bf);
  int n0 = blockIdx.x * 8;
  for (int e = tid; e < 512; e += 256) {
    int p = e >> 6, i = e & 63;
    int n = n0 + p;
    sf[p][i] = (n < Npts) ? ldf(feats, (size_t)n * 64 + i, bf) : 0.f;
  }
  __syncthreads();
  int p = tid >> 5, c = tid & 31;
  int n = n0 + p;
  if (n < Npts) {
    float acc = sb[c];
#pragma unroll
    for (int i = 0; i < 64; ++i) acc += sf[p][i] * sW[i * 32 + c];
    fx[(size_t)n * 32 + c] = lrelu(acc);
  }
}

// ---------------------------------------------------------------------------
// K2: per point (one wave each, 4 waves/block), chunk [n0,n1):
//   localized_xyz -> out1 (f32) and LDS; WeightNet -> w[16,16];
//   gather feats_x ; einsum -> nf (bf16, chunk-local)
// ---------------------------------------------------------------------------
__global__ __launch_bounds__(256) void k2_point(
    const void* __restrict__ xyz, const int* __restrict__ nei,
    const float* __restrict__ fx,
    const void* __restrict__ W0, const void* __restrict__ g0, const void* __restrict__ b0,
    const void* __restrict__ W1, const void* __restrict__ g1, const void* __restrict__ b1,
    const void* __restrict__ W2, const void* __restrict__ g2, const void* __restrict__ b2,
    u16* __restrict__ nf16, float* __restrict__ locout, int n0, int n1)
{
  __shared__ float sW0[24], sB0[8], sW1[64], sB1[8], sW2[128], sB2[16];
  __shared__ int   sIdx[4][16];
  __shared__ float sLoc[4][48];
  __shared__ float sHa[4][128];
  __shared__ float sHb[4][128];
  alignas(16) __shared__ float sP[4][256];
  alignas(16) __shared__ float sGF[4][512];

  bool bf = probe_bf16(g0);
  int tid = threadIdx.x;
  if (tid < 24) sW0[tid] = ldf(W0, tid, bf) * ldf(g0, tid & 7, bf);
  else if (tid < 32) sB0[tid - 24] = ldf(b0, tid - 24, bf);
  else if (tid < 96) sW1[tid - 32] = ldf(W1, tid - 32, bf) * ldf(g1, (tid - 32) & 7, bf);
  else if (tid < 104) sB1[tid - 96] = ldf(b1, tid - 96, bf);
  else if (tid < 232) sW2[tid - 104] = ldf(W2, tid - 104, bf) * ldf(g2, (tid - 104) & 15, bf);
  else if (tid < 248) sB2[tid - 232] = ldf(b2, tid - 232, bf);

  int w = tid >> 6, lane = tid & 63;
  int n = n0 + blockIdx.x * 4 + w;
  bool valid = n < n1;

  if (lane < 16) sIdx[w][lane] = valid ? nei[(size_t)n * 16 + lane] : 0;
  __syncthreads();

  if (lane < 48) {
    int k = lane / 3, d = lane - k * 3;
    float v = 0.f;
    if (valid) {
      int m = sIdx[w][k];
      v = ldf(xyz, (size_t)m * 3 + d, bf) - ldf(xyz, (size_t)n * 3 + d, bf);
      locout[(size_t)n * 48 + lane] = v;
    }
    sLoc[w][lane] = v;
  }
  __syncthreads();

#pragma unroll
  for (int r = 0; r < 2; ++r) {
    int o = lane + r * 64;
    int k = o >> 3, j = o & 7;
    float a = sB0[j];
#pragma unroll
    for (int d = 0; d < 3; ++d) a += sLoc[w][k * 3 + d] * sW0[d * 8 + j];
    sHa[w][o] = fmaxf(a, 0.f);
  }
  __syncthreads();
#pragma unroll
  for (int r = 0; r < 2; ++r) {
    int o = lane + r * 64;
    int k = o >> 3, j = o & 7;
    float a = sB1[j];
#pragma unroll
    for (int d = 0; d < 8; ++d) a += sHa[w][k * 8 + d] * sW1[d * 8 + j];
    sHb[w][o] = fmaxf(a, 0.f);
  }
  __syncthreads();
#pragma unroll
  for (int r = 0; r < 4; ++r) {
    int o = lane + r * 64;
    int k = o >> 4, j = o & 15;
    float a = sB2[j];
#pragma unroll
    for (int d = 0; d < 8; ++d) a += sHb[w][k * 8 + d] * sW2[d * 16 + j];
    sP[w][o] = fmaxf(a, 0.f);
  }

  {
    int e0 = lane * 8;
    int k = e0 >> 5, c0 = e0 & 31;
    float4 v0 = make_float4(0.f, 0.f, 0.f, 0.f), v1 = v0;
    if (valid) {
      int m = sIdx[w][k];
      const float4* src = reinterpret_cast<const float4*>(fx + (size_t)m * 32 + c0);
      v0 = src[0]; v1 = src[1];
    }
    float4* dst = reinterpret_cast<float4*>(&sGF[w][e0]);
    dst[0] = v0; dst[1] = v1;
  }
  __syncthreads();

  {
    int c = lane >> 1, mb = (lane & 1) * 8;
    float acc[8] = {0.f, 0.f, 0.f, 0.f, 0.f, 0.f, 0.f, 0.f};
#pragma unroll
    for (int k = 0; k < 16; ++k) {
      float f = sGF[w][k * 32 + c];
      const float4* pw = reinterpret_cast<const float4*>(&sP[w][k * 16 + mb]);
      float4 w0 = pw[0], w1 = pw[1];
      acc[0] += f * w0.x; acc[1] += f * w0.y; acc[2] += f * w0.z; acc[3] += f * w0.w;
      acc[4] += f * w1.x; acc[5] += f * w1.y; acc[6] += f * w1.z; acc[7] += f * w1.w;
    }
    if (valid) {
      bf16x8 pk;
#pragma unroll
      for (int e = 0; e < 8; ++e) pk[e] = (short)f2bf(acc[e]);
      *reinterpret_cast<bf16x8*>(nf16 + (size_t)(n - n0) * 512 + (c * 16 + mb)) = pk;
    }
  }
}

// ---------------------------------------------------------------------------
// K3: MFMA bf16 GEMM  h[cnt,64] = relu(nf16[cnt,512] @ (W_lin*g) + b), bf16 out
// 256 thr = 4 waves; tile BM=128 x BN=64; K-step 32 via mfma_f32_16x16x32_bf16.
// Full B staged once (64KB); A per 64-k slab (16KB); XOR-swizzled 16B chunks.
// ---------------------------------------------------------------------------
__global__ __launch_bounds__(256) void k3_gemm(
    const u16* __restrict__ nf, const void* __restrict__ WL,
    const void* __restrict__ gl, const void* __restrict__ bl,
    u16* __restrict__ h, int cnt)
{
  alignas(16) __shared__ u16 As[128 * 64];   // [row][kchunk swizzled]
  alignas(16) __shared__ u16 Bs[64 * 512];   // [col][kchunk swizzled]
  bool bf = probe_bf16(gl);
  int t = threadIdx.x;
  int lane = t & 63, w = t >> 6;
  int m0 = blockIdx.x * 128;

  // ---- stage all of B once (g-folded, bf16, swizzled) ----
  {
    int c = t & 63, kh = t >> 6;          // column, k-quarter
    float gc = ldf(gl, c, bf);
    int k0 = kh * 128;
#pragma unroll
    for (int q = 0; q < 16; ++q) {
      int kbase = k0 + q * 8;
      bf16x8 pk;
#pragma unroll
      for (int e = 0; e < 8; ++e)
        pk[e] = (short)f2bf(ldf(WL, (size_t)(kbase + e) * 64 + c, bf) * gc);
      int chunk = (kbase >> 3) ^ (c & 7);
      *reinterpret_cast<bf16x8*>(&Bs[c * 512 + chunk * 8]) = pk;
    }
  }

  f32x4 acc[2][4];
#pragma unroll
  for (int mi = 0; mi < 2; ++mi)
#pragma unroll
    for (int ni = 0; ni < 4; ++ni) acc[mi][ni] = (f32x4){0.f, 0.f, 0.f, 0.f};

  int mrow = t >> 1;            // staging row 0..127
  int half = t & 1;             // k-half of the 64-k slab

  for (int kb = 0; kb < 512; kb += 64) {
    __syncthreads();  // previous slab consumed (and Bs ready on first iter)
    // ---- stage A slab: rows m0..m0+127, k in [kb, kb+64) ----
    {
      int gm = m0 + mrow;
      if (gm >= cnt) gm = cnt - 1;        // clamp: safe reads, rows unused
      const u16* src = nf + (size_t)gm * 512 + kb + half * 32;
#pragma unroll
      for (int q = 0; q < 4; ++q) {
        bf16x8 v = *reinterpret_cast<const bf16x8*>(src + q * 8);
        int chunk = (half * 4 + q) ^ (mrow & 7);
        *reinterpret_cast<bf16x8*>(&As[mrow * 64 + chunk * 8]) = v;
      }
    }
    __syncthreads();
    // ---- compute: two K-steps of 32 ----
#pragma unroll
    for (int ks = 0; ks < 2; ++ks) {
      int qg = lane >> 4;                 // k-group 0..3
      bf16x8 a[2];
#pragma unroll
      for (int mi = 0; mi < 2; ++mi) {
        int row = w * 32 + mi * 16 + (lane & 15);
        int chunk = (ks * 4 + qg) ^ (row & 7);
        a[mi] = *reinterpret_cast<const bf16x8*>(&As[row * 64 + chunk * 8]);
      }
      bf16x8 bfr[4];
#pragma unroll
      for (int ni = 0; ni < 4; ++ni) {
        int col = ni * 16 + (lane & 15);
        int chunk = ((kb >> 3) + ks * 4 + qg) ^ (col & 7);
        bfr[ni] = *reinterpret_cast<const bf16x8*>(&Bs[col * 512 + chunk * 8]);
      }
#pragma unroll
      for (int mi = 0; mi < 2; ++mi)
#pragma unroll
        for (int ni = 0; ni < 4; ++ni)
          acc[mi][ni] = __builtin_amdgcn_mfma_f32_16x16x32_bf16(
              a[mi], bfr[ni], acc[mi][ni], 0, 0, 0);
    }
  }

  // ---- epilogue: C/D layout col=lane&15, row=(lane>>4)*4+reg; bf16 out ----
  int colb = lane & 15, rq = lane >> 4;
  float bias[4];
#pragma unroll
  for (int ni = 0; ni < 4; ++ni) bias[ni] = ldf(bl, ni * 16 + colb, bf);
#pragma unroll
  for (int mi = 0; mi < 2; ++mi) {
#pragma unroll
    for (int v = 0; v < 4; ++v) {
      int m = m0 + w * 32 + mi * 16 + rq * 4 + v;
      if (m < cnt) {
#pragma unroll
        for (int ni = 0; ni < 4; ++ni) {
          int j = ni * 16 + colb;
          h[(size_t)m * 64 + j] = f2bf(fmaxf(acc[mi][ni][v] + bias[ni], 0.f));
        }
      }
    }
  }
}

// ---------------------------------------------------------------------------
// K4: MFMA bf16 GEMM  out[cnt,128] = lrelu([h|feats] @ [[Wu2*g];[Wsc*g]] + b)
// BM=128 BN=128, K=128 staged entirely: As[row][128] 32KB (h | feats),
// Bs[col][128] 32KB (Wu2;Wsc g-folded). XOR-swizzled 16B chunks.
// 4 waves; per wave 2 m-frags x 8 n-frags x 4 K-steps = 64 MFMAs.
// ---------------------------------------------------------------------------
__global__ __launch_bounds__(256) void k4_gemm(
    const u16* __restrict__ hb, const void* __restrict__ feats,
    const void* __restrict__ Wu2, const void* __restrict__ gu2, const void* __restrict__ bu2,
    const void* __restrict__ Wsc, const void* __restrict__ gsc, const void* __restrict__ bsc,
    float* __restrict__ out, int n0c, int cnt)
{
  alignas(16) __shared__ u16 As[128 * 128];  // [row][kchunk swizzled]
  alignas(16) __shared__ u16 Bs[128 * 128];  // [col][kchunk swizzled]
  bool bf = probe_bf16(gu2);
  int t = threadIdx.x;
  int lane = t & 63, w = t >> 6;
  int m0 = blockIdx.x * 128;

  // ---- stage B: k<64 from Wu2*gu2, k>=64 from Wsc*gsc ----
  {
    int c = t & 127, kh = t >> 7;          // column, k-half
    const void* Wsel = kh ? Wsc : Wu2;
    const void* gsel = kh ? gsc : gu2;
    float gc = ldf(gsel, c, bf);
#pragma unroll
    for (int q = 0; q < 8; ++q) {
      bf16x8 pk;
#pragma unroll
      for (int e = 0; e < 8; ++e)
        pk[e] = (short)f2bf(ldf(Wsel, (size_t)(q * 8 + e) * 128 + c, bf) * gc);
      int chunk = (kh * 8 + q) ^ (c & 7);
      *reinterpret_cast<bf16x8*>(&Bs[c * 128 + chunk * 8]) = pk;
    }
  }
  // ---- stage A: row r, k<64 from hb (bf16), k>=64 from feats ----
  {
    int r = t >> 1, half = t & 1;
    int gm = m0 + r;
    if (gm >= cnt) gm = cnt - 1;           // clamp: safe reads, rows unused
    if (half == 0) {
      const u16* src = hb + (size_t)gm * 64;
#pragma unroll
      for (int q = 0; q < 8; ++q) {
        bf16x8 v = *reinterpret_cast<const bf16x8*>(src + q * 8);
        int chunk = q ^ (r & 7);
        *reinterpret_cast<bf16x8*>(&As[r * 128 + chunk * 8]) = v;
      }
    } else if (bf) {
      const u16* src = (const u16*)feats + (size_t)(n0c + gm) * 64;
#pragma unroll
      for (int q = 0; q < 8; ++q) {
        bf16x8 v = *reinterpret_cast<const bf16x8*>(src + q * 8);
        int chunk = (8 + q) ^ (r & 7);
        *reinterpret_cast<bf16x8*>(&As[r * 128 + chunk * 8]) = v;
      }
    } else {
      const float* src = (const float*)feats + (size_t)(n0c + gm) * 64;
#pragma unroll
      for (int q = 0; q < 8; ++q) {
        bf16x8 pk;
#pragma unroll
        for (int e = 0; e < 8; ++e) pk[e] = (short)f2bf(src[q * 8 + e]);
        int chunk = (8 + q) ^ (r & 7);
        *reinterpret_cast<bf16x8*>(&As[r * 128 + chunk * 8]) = pk;
      }
    }
  }
  __syncthreads();

  f32x4 acc[2][8];
#pragma unroll
  for (int mi = 0; mi < 2; ++mi)
#pragma unroll
    for (int ni = 0; ni < 8; ++ni) acc[mi][ni] = (f32x4){0.f, 0.f, 0.f, 0.f};

  int qg = lane >> 4;
#pragma unroll
  for (int ks = 0; ks < 4; ++ks) {
    bf16x8 a[2];
#pragma unroll
    for (int mi = 0; mi < 2; ++mi) {
      int row = w * 32 + mi * 16 + (lane & 15);
      int chunk = (ks * 4 + qg) ^ (row & 7);
      a[mi] = *reinterpret_cast<const bf16x8*>(&As[row * 128 + chunk * 8]);
    }
#pragma unroll
    for (int ni = 0; ni < 8; ++ni) {
      int col = ni * 16 + (lane & 15);
      int chunk = (ks * 4 + qg) ^ (col & 7);
      bf16x8 b = *reinterpret_cast<const bf16x8*>(&Bs[col * 128 + chunk * 8]);
      acc[0][ni] = __builtin_amdgcn_mfma_f32_16x16x32_bf16(a[0], b, acc[0][ni], 0, 0, 0);
      acc[1][ni] = __builtin_amdgcn_mfma_f32_16x16x32_bf16(a[1], b, acc[1][ni], 0, 0, 0);
    }
  }

  // ---- epilogue ----
  int colb = lane & 15, rq = lane >> 4;
  float bias[8];
#pragma unroll
  for (int ni = 0; ni < 8; ++ni) {
    int c = ni * 16 + colb;
    bias[ni] = ldf(bu2, c, bf) + ldf(bsc, c, bf);
  }
#pragma unroll
  for (int mi = 0; mi < 2; ++mi) {
#pragma unroll
    for (int v = 0; v < 4; ++v) {
      int m = m0 + w * 32 + mi * 16 + rq * 4 + v;
      if (m < cnt) {
        float* orow = out + (size_t)(n0c + m) * 128;
#pragma unroll
        for (int ni = 0; ni < 8; ++ni)
          orow[ni * 16 + colb] = lrelu(acc[mi][ni][v] + bias[ni]);
      }
    }
  }
}

extern "C" void kernel_launch(void* const* d_in, const int* in_sizes, int n_in,
                              void* d_out, int out_size, void* d_ws, size_t ws_size,
                              hipStream_t stream) {
  const void* xyz   = d_in[0];
  const void* feats = d_in[1];
  const int*  nei   = (const int*)d_in[2];
  const void* W_u1  = d_in[3];
  const void* g_u1  = d_in[4];
  const void* b_u1  = d_in[5];
  const void* W_wn0 = d_in[6];
  const void* g_wn0 = d_in[7];
  const void* b_wn0 = d_in[8];
  const void* W_wn1 = d_in[9];
  const void* g_wn1 = d_in[10];
  const void* b_wn1 = d_in[11];
  const void* W_wn2 = d_in[12];
  const void* g_wn2 = d_in[13];
  const void* b_wn2 = d_in[14];
  const void* W_lin = d_in[15];
  const void* g_lin = d_in[16];
  const void* b_lin = d_in[17];
  const void* W_u2  = d_in[18];
  const void* g_u2  = d_in[19];
  const void* b_u2  = d_in[20];
  const void* W_sc  = d_in[21];
  const void* g_sc  = d_in[22];
  const void* b_sc  = d_in[23];

  int Npts = in_sizes[0] / 3;

  float* out0 = (float*)d_out;                 // [N,128] f32
  float* out1 = out0 + (size_t)Npts * 128;     // [N,16,3] f32

  float* fx = (float*)d_ws;                    // [N,32] f32
  size_t fx_bytes = (size_t)Npts * 32 * 4;
  size_t avail = (ws_size > fx_bytes) ? (ws_size - fx_bytes) : 0;
  size_t per_pt = (size_t)512 * 2 + (size_t)64 * 2;  // nf bf16 + h bf16 = 1152 B/pt
  long long cN = (long long)(avail / per_pt);
  if (cN < 1) cN = 1;
  if (cN > Npts) cN = Npts;
  int chunkN = (int)cN;

  u16* nf16 = (u16*)(fx + (size_t)Npts * 32);
  u16* hb   = nf16 + (size_t)chunkN * 512;

  k1_unary<<<(Npts + 7) / 8, 256, 0, stream>>>(feats, W_u1, g_u1, b_u1, fx, Npts);

  for (int n0 = 0; n0 < Npts; n0 += chunkN) {
    int n1 = n0 + chunkN;
    if (n1 > Npts) n1 = Npts;
    int cnt = n1 - n0;
    k2_point<<<(cnt + 3) / 4, 256, 0, stream>>>(
        xyz, nei, fx,
        W_wn0, g_wn0, b_wn0, W_wn1, g_wn1, b_wn1, W_wn2, g_wn2, b_wn2,
        nf16, out1, n0, n1);
    k3_gemm<<<(cnt + 127) / 128, 256, 0, stream>>>(nf16, W_lin, g_lin, b_lin, hb, cnt);
    k4_gemm<<<(cnt + 127) / 128, 256, 0, stream>>>(hb, feats, W_u2, g_u2, b_u2,
                                                   W_sc, g_sc, b_sc, out0, n0, cnt);
  }
}

// Round 4
// 444.140 us; speedup vs baseline: 2.2963x; 1.0308x over previous
//
#include <hip/hip_runtime.h>
#include <stdint.h>

typedef unsigned short u16;
typedef unsigned int   u32;

typedef __attribute__((ext_vector_type(8))) short bf16x8;
typedef __attribute__((ext_vector_type(4))) float f32x4;

// N = 160000, K = 16, C_IN = 64, C1 = 32, C_MID = 16, C2 = 64, C_OUT = 128
// Harness delivers bf16 inputs (probe fires). fx, nf, h intermediates stored
// bf16 -> k2 einsum, k3, k4 all run on the matrix pipe.

__device__ __forceinline__ float bf2f(u16 h) {
  return __uint_as_float(((u32)h) << 16);
}
__device__ __forceinline__ float lrelu(float x) { return x > 0.f ? x : 0.1f * x; }

__device__ __forceinline__ float ldf(const void* p, size_t i, bool bf) {
  return bf ? bf2f(((const u16*)p)[i]) : ((const float*)p)[i];
}
__device__ __forceinline__ bool probe_bf16(const void* g) {
  return ((*(const u32*)g) & 0xFFFFu) == 0x3F80u;
}
__device__ __forceinline__ u16 f2bf(float x) {  // round-to-nearest-even
  u32 u = __float_as_uint(x);
  return (u16)((u + 0x7FFFu + ((u >> 16) & 1u)) >> 16);
}

// ---------------------------------------------------------------------------
// K1: feats_x = lrelu(feats @ (W_u1 * g) + b)   [N,64] -> [N,32], bf16 out
// ---------------------------------------------------------------------------
__global__ __launch_bounds__(256) void k1_unary(
    const void* __restrict__ feats, const void* __restrict__ W,
    const void* __restrict__ g, const void* __restrict__ b,
    u16* __restrict__ fx, int Npts)
{
  __shared__ float sW[64 * 32];
  __shared__ float sb[32];
  __shared__ float sf[8][64];
  bool bf = probe_bf16(g);
  int tid = threadIdx.x;
  for (int e = tid; e < 2048; e += 256) sW[e] = ldf(W, e, bf) * ldf(g, e & 31, bf);
  if (tid < 32) sb[tid] = ldf(b, tid, bf);
  int n0 = blockIdx.x * 8;
  for (int e = tid; e < 512; e += 256) {
    int p = e >> 6, i = e & 63;
    int n = n0 + p;
    sf[p][i] = (n < Npts) ? ldf(feats, (size_t)n * 64 + i, bf) : 0.f;
  }
  __syncthreads();
  int p = tid >> 5, c = tid & 31;
  int n = n0 + p;
  if (n < Npts) {
    float acc = sb[c];
#pragma unroll
    for (int i = 0; i < 64; ++i) acc += sf[p][i] * sW[i * 32 + c];
    fx[(size_t)n * 32 + c] = f2bf(lrelu(acc));
  }
}

// ---------------------------------------------------------------------------
// K2: per point (one wave each, 4 waves/block), chunk [n0,n1):
//   localized_xyz -> out1 (f32) and LDS; WeightNet -> sPT (bf16, [j][k]);
//   gather fx (bf16) -> sGFT transposed ([c][k]); einsum via 2x MFMA -> nf bf16
// LDS stride 24 u16 (48 B) keeps b128 fragment reads 16-B aligned, ~2-way.
// ---------------------------------------------------------------------------
__global__ __launch_bounds__(256) void k2_point(
    const void* __restrict__ xyz, const int* __restrict__ nei,
    const u16* __restrict__ fx,
    const void* __restrict__ W0, const void* __restrict__ g0, const void* __restrict__ b0,
    const void* __restrict__ W1, const void* __restrict__ g1, const void* __restrict__ b1,
    const void* __restrict__ W2, const void* __restrict__ g2, const void* __restrict__ b2,
    u16* __restrict__ nf16, float* __restrict__ locout, int n0, int n1)
{
  __shared__ float sW0[24], sB0[8], sW1[64], sB1[8], sW2[128], sB2[16];
  __shared__ int   sIdx[4][16];
  __shared__ float sLoc[4][48];
  __shared__ float sHa[4][128];
  __shared__ float sHb[4][128];
  alignas(16) __shared__ u16 sPT[4][16 * 24];   // [w][j*24 + k]  (wgt^T, bf16)
  alignas(16) __shared__ u16 sGFT[4][32 * 24];  // [w][c*24 + k]  (gf^T, bf16)

  bool bf = probe_bf16(g0);
  int tid = threadIdx.x;
  if (tid < 24) sW0[tid] = ldf(W0, tid, bf) * ldf(g0, tid & 7, bf);
  else if (tid < 32) sB0[tid - 24] = ldf(b0, tid - 24, bf);
  else if (tid < 96) sW1[tid - 32] = ldf(W1, tid - 32, bf) * ldf(g1, (tid - 32) & 7, bf);
  else if (tid < 104) sB1[tid - 96] = ldf(b1, tid - 96, bf);
  else if (tid < 232) sW2[tid - 104] = ldf(W2, tid - 104, bf) * ldf(g2, (tid - 104) & 15, bf);
  else if (tid < 248) sB2[tid - 232] = ldf(b2, tid - 232, bf);

  int w = tid >> 6, lane = tid & 63;
  int n = n0 + blockIdx.x * 4 + w;
  bool valid = n < n1;

  if (lane < 16) sIdx[w][lane] = valid ? nei[(size_t)n * 16 + lane] : 0;
  __syncthreads();

  if (lane < 48) {
    int k = lane / 3, d = lane - k * 3;
    float v = 0.f;
    if (valid) {
      int m = sIdx[w][k];
      v = ldf(xyz, (size_t)m * 3 + d, bf) - ldf(xyz, (size_t)n * 3 + d, bf);
      locout[(size_t)n * 48 + lane] = v;
    }
    sLoc[w][lane] = v;
  }

  // ---- gather fx rows (bf16) and scatter transposed into sGFT ----
  {
    int k = lane & 15, cg = lane >> 4;      // neighbor k, channel-group
    int m = sIdx[w][k];
    bf16x8 v = *reinterpret_cast<const bf16x8*>(fx + (size_t)m * 32 + cg * 8);
#pragma unroll
    for (int e = 0; e < 8; ++e)
      sGFT[w][(cg * 8 + e) * 24 + k] = (u16)v[e];
  }
  __syncthreads();

#pragma unroll
  for (int r = 0; r < 2; ++r) {
    int o = lane + r * 64;
    int k = o >> 3, j = o & 7;
    float a = sB0[j];
#pragma unroll
    for (int d = 0; d < 3; ++d) a += sLoc[w][k * 3 + d] * sW0[d * 8 + j];
    sHa[w][o] = fmaxf(a, 0.f);
  }
  __syncthreads();
#pragma unroll
  for (int r = 0; r < 2; ++r) {
    int o = lane + r * 64;
    int k = o >> 3, j = o & 7;
    float a = sB1[j];
#pragma unroll
    for (int d = 0; d < 8; ++d) a += sHa[w][k * 8 + d] * sW1[d * 8 + j];
    sHb[w][o] = fmaxf(a, 0.f);
  }
  __syncthreads();
#pragma unroll
  for (int r = 0; r < 4; ++r) {
    int o = lane + r * 64;
    int k = o >> 4, j = o & 15;
    float a = sB2[j];
#pragma unroll
    for (int d = 0; d < 8; ++d) a += sHb[w][k * 8 + d] * sW2[d * 16 + j];
    sPT[w][j * 24 + k] = f2bf(fmaxf(a, 0.f));   // transposed bf16
  }
  __syncthreads();

  // ---- einsum via MFMA: nf[c][j] = sum_k gf^T[c][k] * wgt[k][j] ----
  {
    int kgrp = lane >> 4;       // 0..3 ; k = kgrp*8+e, only k<16 real
    int cb = lane & 15;
    bf16x8 a0 = (bf16x8){0,0,0,0,0,0,0,0};
    bf16x8 a1 = a0, b = a0;
    if (kgrp < 2) {
      a0 = *reinterpret_cast<const bf16x8*>(&sGFT[w][(cb)      * 24 + kgrp * 8]);
      a1 = *reinterpret_cast<const bf16x8*>(&sGFT[w][(16 + cb) * 24 + kgrp * 8]);
      b  = *reinterpret_cast<const bf16x8*>(&sPT [w][(cb)      * 24 + kgrp * 8]);
    }
    f32x4 acc0 = (f32x4){0.f, 0.f, 0.f, 0.f};
    f32x4 acc1 = acc0;
    acc0 = __builtin_amdgcn_mfma_f32_16x16x32_bf16(a0, b, acc0, 0, 0, 0);
    acc1 = __builtin_amdgcn_mfma_f32_16x16x32_bf16(a1, b, acc1, 0, 0, 0);
    if (valid) {
      u16* dst = nf16 + (size_t)(n - n0) * 512;
      int rq = lane >> 4;
#pragma unroll
      for (int v = 0; v < 4; ++v) {
        int c0 = rq * 4 + v;          // tile 0: c 0..15
        int c1 = 16 + rq * 4 + v;     // tile 1: c 16..31
        dst[c0 * 16 + cb] = f2bf(acc0[v]);
        dst[c1 * 16 + cb] = f2bf(acc1[v]);
      }
    }
  }
}

// ---------------------------------------------------------------------------
// K3: MFMA bf16 GEMM  h[cnt,64] = relu(nf16[cnt,512] @ (W_lin*g) + b), bf16 out
// 256 thr = 4 waves; tile BM=128 x BN=64; K-step 32 via mfma_f32_16x16x32_bf16.
// Full B staged once (64KB); A per 64-k slab (16KB); XOR-swizzled 16B chunks.
// ---------------------------------------------------------------------------
__global__ __launch_bounds__(256) void k3_gemm(
    const u16* __restrict__ nf, const void* __restrict__ WL,
    const void* __restrict__ gl, const void* __restrict__ bl,
    u16* __restrict__ h, int cnt)
{
  alignas(16) __shared__ u16 As[128 * 64];   // [row][kchunk swizzled]
  alignas(16) __shared__ u16 Bs[64 * 512];   // [col][kchunk swizzled]
  bool bf = probe_bf16(gl);
  int t = threadIdx.x;
  int lane = t & 63, w = t >> 6;
  int m0 = blockIdx.x * 128;

  // ---- stage all of B once (g-folded, bf16, swizzled) ----
  {
    int c = t & 63, kh = t >> 6;          // column, k-quarter
    float gc = ldf(gl, c, bf);
    int k0 = kh * 128;
#pragma unroll
    for (int q = 0; q < 16; ++q) {
      int kbase = k0 + q * 8;
      bf16x8 pk;
#pragma unroll
      for (int e = 0; e < 8; ++e)
        pk[e] = (short)f2bf(ldf(WL, (size_t)(kbase + e) * 64 + c, bf) * gc);
      int chunk = (kbase >> 3) ^ (c & 7);
      *reinterpret_cast<bf16x8*>(&Bs[c * 512 + chunk * 8]) = pk;
    }
  }

  f32x4 acc[2][4];
#pragma unroll
  for (int mi = 0; mi < 2; ++mi)
#pragma unroll
    for (int ni = 0; ni < 4; ++ni) acc[mi][ni] = (f32x4){0.f, 0.f, 0.f, 0.f};

  int mrow = t >> 1;            // staging row 0..127
  int half = t & 1;             // k-half of the 64-k slab

  for (int kb = 0; kb < 512; kb += 64) {
    __syncthreads();  // previous slab consumed (and Bs ready on first iter)
    // ---- stage A slab: rows m0..m0+127, k in [kb, kb+64) ----
    {
      int gm = m0 + mrow;
      if (gm >= cnt) gm = cnt - 1;        // clamp: safe reads, rows unused
      const u16* src = nf + (size_t)gm * 512 + kb + half * 32;
#pragma unroll
      for (int q = 0; q < 4; ++q) {
        bf16x8 v = *reinterpret_cast<const bf16x8*>(src + q * 8);
        int chunk = (half * 4 + q) ^ (mrow & 7);
        *reinterpret_cast<bf16x8*>(&As[mrow * 64 + chunk * 8]) = v;
      }
    }
    __syncthreads();
    // ---- compute: two K-steps of 32 ----
#pragma unroll
    for (int ks = 0; ks < 2; ++ks) {
      int qg = lane >> 4;                 // k-group 0..3
      bf16x8 a[2];
#pragma unroll
      for (int mi = 0; mi < 2; ++mi) {
        int row = w * 32 + mi * 16 + (lane & 15);
        int chunk = (ks * 4 + qg) ^ (row & 7);
        a[mi] = *reinterpret_cast<const bf16x8*>(&As[row * 64 + chunk * 8]);
      }
      bf16x8 bfr[4];
#pragma unroll
      for (int ni = 0; ni < 4; ++ni) {
        int col = ni * 16 + (lane & 15);
        int chunk = ((kb >> 3) + ks * 4 + qg) ^ (col & 7);
        bfr[ni] = *reinterpret_cast<const bf16x8*>(&Bs[col * 512 + chunk * 8]);
      }
#pragma unroll
      for (int mi = 0; mi < 2; ++mi)
#pragma unroll
        for (int ni = 0; ni < 4; ++ni)
          acc[mi][ni] = __builtin_amdgcn_mfma_f32_16x16x32_bf16(
              a[mi], bfr[ni], acc[mi][ni], 0, 0, 0);
    }
  }

  // ---- epilogue: C/D layout col=lane&15, row=(lane>>4)*4+reg; bf16 out ----
  int colb = lane & 15, rq = lane >> 4;
  float bias[4];
#pragma unroll
  for (int ni = 0; ni < 4; ++ni) bias[ni] = ldf(bl, ni * 16 + colb, bf);
#pragma unroll
  for (int mi = 0; mi < 2; ++mi) {
#pragma unroll
    for (int v = 0; v < 4; ++v) {
      int m = m0 + w * 32 + mi * 16 + rq * 4 + v;
      if (m < cnt) {
#pragma unroll
        for (int ni = 0; ni < 4; ++ni) {
          int j = ni * 16 + colb;
          h[(size_t)m * 64 + j] = f2bf(fmaxf(acc[mi][ni][v] + bias[ni], 0.f));
        }
      }
    }
  }
}

// ---------------------------------------------------------------------------
// K4: MFMA bf16 GEMM  out[cnt,128] = lrelu([h|feats] @ [[Wu2*g];[Wsc*g]] + b)
// BM=128 BN=128, K=128 staged entirely: As[row][128] 32KB (h | feats),
// Bs[col][128] 32KB (Wu2;Wsc g-folded). XOR-swizzled 16B chunks.
// 4 waves; per wave 2 m-frags x 8 n-frags x 4 K-steps = 64 MFMAs.
// ---------------------------------------------------------------------------
__global__ __launch_bounds__(256) void k4_gemm(
    const u16* __restrict__ hb, const void* __restrict__ feats,
    const void* __restrict__ Wu2, const void* __restrict__ gu2, const void* __restrict__ bu2,
    const void* __restrict__ Wsc, const void* __restrict__ gsc, const void* __restrict__ bsc,
    float* __restrict__ out, int n0c, int cnt)
{
  alignas(16) __shared__ u16 As[128 * 128];  // [row][kchunk swizzled]
  alignas(16) __shared__ u16 Bs[128 * 128];  // [col][kchunk swizzled]
  bool bf = probe_bf16(gu2);
  int t = threadIdx.x;
  int lane = t & 63, w = t >> 6;
  int m0 = blockIdx.x * 128;

  // ---- stage B: k<64 from Wu2*gu2, k>=64 from Wsc*gsc ----
  {
    int c = t & 127, kh = t >> 7;          // column, k-half
    const void* Wsel = kh ? Wsc : Wu2;
    const void* gsel = kh ? gsc : gu2;
    float gc = ldf(gsel, c, bf);
#pragma unroll
    for (int q = 0; q < 8; ++q) {
      bf16x8 pk;
#pragma unroll
      for (int e = 0; e < 8; ++e)
        pk[e] = (short)f2bf(ldf(Wsel, (size_t)(q * 8 + e) * 128 + c, bf) * gc);
      int chunk = (kh * 8 + q) ^ (c & 7);
      *reinterpret_cast<bf16x8*>(&Bs[c * 128 + chunk * 8]) = pk;
    }
  }
  // ---- stage A: row r, k<64 from hb (bf16), k>=64 from feats ----
  {
    int r = t >> 1, half = t & 1;
    int gm = m0 + r;
    if (gm >= cnt) gm = cnt - 1;           // clamp: safe reads, rows unused
    if (half == 0) {
      const u16* src = hb + (size_t)gm * 64;
#pragma unroll
      for (int q = 0; q < 8; ++q) {
        bf16x8 v = *reinterpret_cast<const bf16x8*>(src + q * 8);
        int chunk = q ^ (r & 7);
        *reinterpret_cast<bf16x8*>(&As[r * 128 + chunk * 8]) = v;
      }
    } else if (bf) {
      const u16* src = (const u16*)feats + (size_t)(n0c + gm) * 64;
#pragma unroll
      for (int q = 0; q < 8; ++q) {
        bf16x8 v = *reinterpret_cast<const bf16x8*>(src + q * 8);
        int chunk = (8 + q) ^ (r & 7);
        *reinterpret_cast<bf16x8*>(&As[r * 128 + chunk * 8]) = v;
      }
    } else {
      const float* src = (const float*)feats + (size_t)(n0c + gm) * 64;
#pragma unroll
      for (int q = 0; q < 8; ++q) {
        bf16x8 pk;
#pragma unroll
        for (int e = 0; e < 8; ++e) pk[e] = (short)f2bf(src[q * 8 + e]);
        int chunk = (8 + q) ^ (r & 7);
        *reinterpret_cast<bf16x8*>(&As[r * 128 + chunk * 8]) = pk;
      }
    }
  }
  __syncthreads();

  f32x4 acc[2][8];
#pragma unroll
  for (int mi = 0; mi < 2; ++mi)
#pragma unroll
    for (int ni = 0; ni < 8; ++ni) acc[mi][ni] = (f32x4){0.f, 0.f, 0.f, 0.f};

  int qg = lane >> 4;
#pragma unroll
  for (int ks = 0; ks < 4; ++ks) {
    bf16x8 a[2];
#pragma unroll
    for (int mi = 0; mi < 2; ++mi) {
      int row = w * 32 + mi * 16 + (lane & 15);
      int chunk = (ks * 4 + qg) ^ (row & 7);
      a[mi] = *reinterpret_cast<const bf16x8*>(&As[row * 128 + chunk * 8]);
    }
#pragma unroll
    for (int ni = 0; ni < 8; ++ni) {
      int col = ni * 16 + (lane & 15);
      int chunk = (ks * 4 + qg) ^ (col & 7);
      bf16x8 b = *reinterpret_cast<const bf16x8*>(&Bs[col * 128 + chunk * 8]);
      acc[0][ni] = __builtin_amdgcn_mfma_f32_16x16x32_bf16(a[0], b, acc[0][ni], 0, 0, 0);
      acc[1][ni] = __builtin_amdgcn_mfma_f32_16x16x32_bf16(a[1], b, acc[1][ni], 0, 0, 0);
    }
  }

  // ---- epilogue ----
  int colb = lane & 15, rq = lane >> 4;
  float bias[8];
#pragma unroll
  for (int ni = 0; ni < 8; ++ni) {
    int c = ni * 16 + colb;
    bias[ni] = ldf(bu2, c, bf) + ldf(bsc, c, bf);
  }
#pragma unroll
  for (int mi = 0; mi < 2; ++mi) {
#pragma unroll
    for (int v = 0; v < 4; ++v) {
      int m = m0 + w * 32 + mi * 16 + rq * 4 + v;
      if (m < cnt) {
        float* orow = out + (size_t)(n0c + m) * 128;
#pragma unroll
        for (int ni = 0; ni < 8; ++ni)
          orow[ni * 16 + colb] = lrelu(acc[mi][ni][v] + bias[ni]);
      }
    }
  }
}

extern "C" void kernel_launch(void* const* d_in, const int* in_sizes, int n_in,
                              void* d_out, int out_size, void* d_ws, size_t ws_size,
                              hipStream_t stream) {
  const void* xyz   = d_in[0];
  const void* feats = d_in[1];
  const int*  nei   = (const int*)d_in[2];
  const void* W_u1  = d_in[3];
  const void* g_u1  = d_in[4];
  const void* b_u1  = d_in[5];
  const void* W_wn0 = d_in[6];
  const void* g_wn0 = d_in[7];
  const void* b_wn0 = d_in[8];
  const void* W_wn1 = d_in[9];
  const void* g_wn1 = d_in[10];
  const void* b_wn1 = d_in[11];
  const void* W_wn2 = d_in[12];
  const void* g_wn2 = d_in[13];
  const void* b_wn2 = d_in[14];
  const void* W_lin = d_in[15];
  const void* g_lin = d_in[16];
  const void* b_lin = d_in[17];
  const void* W_u2  = d_in[18];
  const void* g_u2  = d_in[19];
  const void* b_u2  = d_in[20];
  const void* W_sc  = d_in[21];
  const void* g_sc  = d_in[22];
  const void* b_sc  = d_in[23];

  int Npts = in_sizes[0] / 3;

  float* out0 = (float*)d_out;                 // [N,128] f32
  float* out1 = out0 + (size_t)Npts * 128;     // [N,16,3] f32

  u16* fx = (u16*)d_ws;                        // [N,32] bf16
  size_t fx_bytes = (size_t)Npts * 32 * 2;
  size_t avail = (ws_size > fx_bytes) ? (ws_size - fx_bytes) : 0;
  size_t per_pt = (size_t)512 * 2 + (size_t)64 * 2;  // nf bf16 + h bf16 = 1152 B/pt
  long long cN = (long long)(avail / per_pt);
  if (cN < 1) cN = 1;
  if (cN > Npts) cN = Npts;
  int chunkN = (int)cN;

  u16* nf16 = fx + (size_t)Npts * 32;
  u16* hb   = nf16 + (size_t)chunkN * 512;

  k1_unary<<<(Npts + 7) / 8, 256, 0, stream>>>(feats, W_u1, g_u1, b_u1, fx, Npts);

  for (int n0 = 0; n0 < Npts; n0 += chunkN) {
    int n1 = n0 + chunkN;
    if (n1 > Npts) n1 = Npts;
    int cnt = n1 - n0;
    k2_point<<<(cnt + 3) / 4, 256, 0, stream>>>(
        xyz, nei, fx,
        W_wn0, g_wn0, b_wn0, W_wn1, g_wn1, b_wn1, W_wn2, g_wn2, b_wn2,
        nf16, out1, n0, n1);
    k3_gemm<<<(cnt + 127) / 128, 256, 0, stream>>>(nf16, W_lin, g_lin, b_lin, hb, cnt);
    k4_gemm<<<(cnt + 127) / 128, 256, 0, stream>>>(hb, feats, W_u2, g_u2, b_u2,
                                                   W_sc, g_sc, b_sc, out0, n0, cnt);
  }
}

// Round 5
// 399.150 us; speedup vs baseline: 2.5552x; 1.1127x over previous
//
#include <hip/hip_runtime.h>
#include <stdint.h>

typedef unsigned short u16;
typedef unsigned int   u32;

typedef __attribute__((ext_vector_type(8))) short bf16x8;
typedef __attribute__((ext_vector_type(4))) short bf16x4;
typedef __attribute__((ext_vector_type(4))) float f32x4;

// N = 160000, K = 16, C_IN = 64, C1 = 32, C_MID = 16, C2 = 64, C_OUT = 128
// Harness delivers bf16 inputs (probe fires). fx, nf, h intermediates stored
// bf16 -> k1, k2 einsum, k3, k4 all run on the matrix pipe.
// nf is stored PERMUTED per point: position j*32+c holds new_feat[c][j];
// k3 compensates by permuting W_lin rows during its B-staging (exact).

__device__ __forceinline__ float bf2f(u16 h) {
  return __uint_as_float(((u32)h) << 16);
}
__device__ __forceinline__ float lrelu(float x) { return x > 0.f ? x : 0.1f * x; }

__device__ __forceinline__ float ldf(const void* p, size_t i, bool bf) {
  return bf ? bf2f(((const u16*)p)[i]) : ((const float*)p)[i];
}
__device__ __forceinline__ bool probe_bf16(const void* g) {
  return ((*(const u32*)g) & 0xFFFFu) == 0x3F80u;
}
__device__ __forceinline__ u16 f2bf(float x) {  // round-to-nearest-even
  u32 u = __float_as_uint(x);
  return (u16)((u + 0x7FFFu + ((u >> 16) & 1u)) >> 16);
}

// ---------------------------------------------------------------------------
// K1: MFMA GEMM  fx[N,32] = lrelu(feats[N,64] @ (W_u1*g) + b), bf16 out
// BM=128, K=64 (2 K-steps), N=32. As 16KB + Bs 4KB, XOR-swizzled 16B chunks.
// 4 waves; per wave 2 m-frags x 2 n-frags x 2 k-steps = 8 MFMAs.
// ---------------------------------------------------------------------------
__global__ __launch_bounds__(256) void k1_unary(
    const void* __restrict__ feats, const void* __restrict__ W,
    const void* __restrict__ g, const void* __restrict__ b,
    u16* __restrict__ fx, int Npts)
{
  alignas(16) __shared__ u16 As[128 * 64];  // [row][kchunk swizzled]
  alignas(16) __shared__ u16 Bs[32 * 64];   // [col][kchunk swizzled]
  bool bf = probe_bf16(g);
  int t = threadIdx.x;
  int lane = t & 63, w = t >> 6;
  int m0 = blockIdx.x * 128;

  // ---- stage B (g-folded, bf16, swizzled): thread -> one 8-k chunk ----
  {
    int c = t & 31, kh = t >> 5;          // column 0..31, k-octet 0..7
    float gc = ldf(g, c, bf);
    bf16x8 pk;
#pragma unroll
    for (int e = 0; e < 8; ++e)
      pk[e] = (short)f2bf(ldf(W, (size_t)(kh * 8 + e) * 32 + c, bf) * gc);
    int chunk = kh ^ (c & 7);
    *reinterpret_cast<bf16x8*>(&Bs[c * 64 + chunk * 8]) = pk;
  }
  // ---- stage A: row r, k in [half*32, half*32+32) ----
  {
    int r = t >> 1, half = t & 1;
    int gm = m0 + r;
    if (gm >= Npts) gm = Npts - 1;        // clamp: safe reads, rows unused
    if (bf) {
      const u16* src = (const u16*)feats + (size_t)gm * 64 + half * 32;
#pragma unroll
      for (int q = 0; q < 4; ++q) {
        bf16x8 v = *reinterpret_cast<const bf16x8*>(src + q * 8);
        int chunk = (half * 4 + q) ^ (r & 7);
        *reinterpret_cast<bf16x8*>(&As[r * 64 + chunk * 8]) = v;
      }
    } else {
      const float* src = (const float*)feats + (size_t)gm * 64 + half * 32;
#pragma unroll
      for (int q = 0; q < 4; ++q) {
        bf16x8 pk;
#pragma unroll
        for (int e = 0; e < 8; ++e) pk[e] = (short)f2bf(src[q * 8 + e]);
        int chunk = (half * 4 + q) ^ (r & 7);
        *reinterpret_cast<bf16x8*>(&As[r * 64 + chunk * 8]) = pk;
      }
    }
  }
  __syncthreads();

  f32x4 acc[2][2];
#pragma unroll
  for (int mi = 0; mi < 2; ++mi)
#pragma unroll
    for (int ni = 0; ni < 2; ++ni) acc[mi][ni] = (f32x4){0.f, 0.f, 0.f, 0.f};

  int qg = lane >> 4, cb = lane & 15;
#pragma unroll
  for (int ks = 0; ks < 2; ++ks) {
    bf16x8 a[2];
#pragma unroll
    for (int mi = 0; mi < 2; ++mi) {
      int row = w * 32 + mi * 16 + cb;
      int chunk = (ks * 4 + qg) ^ (row & 7);
      a[mi] = *reinterpret_cast<const bf16x8*>(&As[row * 64 + chunk * 8]);
    }
#pragma unroll
    for (int ni = 0; ni < 2; ++ni) {
      int col = ni * 16 + cb;
      int chunk = (ks * 4 + qg) ^ (col & 7);
      bf16x8 bv = *reinterpret_cast<const bf16x8*>(&Bs[col * 64 + chunk * 8]);
      acc[0][ni] = __builtin_amdgcn_mfma_f32_16x16x32_bf16(a[0], bv, acc[0][ni], 0, 0, 0);
      acc[1][ni] = __builtin_amdgcn_mfma_f32_16x16x32_bf16(a[1], bv, acc[1][ni], 0, 0, 0);
    }
  }

  int rq = lane >> 4;
  float bias[2] = {ldf(b, cb, bf), ldf(b, 16 + cb, bf)};
#pragma unroll
  for (int mi = 0; mi < 2; ++mi) {
#pragma unroll
    for (int v = 0; v < 4; ++v) {
      int m = m0 + w * 32 + mi * 16 + rq * 4 + v;
      if (m < Npts) {
        fx[(size_t)m * 32 + cb]      = f2bf(lrelu(acc[mi][0][v] + bias[0]));
        fx[(size_t)m * 32 + 16 + cb] = f2bf(lrelu(acc[mi][1][v] + bias[1]));
      }
    }
  }
}

// ---------------------------------------------------------------------------
// K2: per point (one wave each, 4 waves/block), chunk [n0,n1):
//   localized_xyz -> out1 (f32) and LDS; WeightNet -> sPT (bf16, [j][k]);
//   gather fx (bf16) -> sGFT transposed ([c][k]); einsum via 2x MFMA ->
//   nf bf16 stored permuted [j*32+c] with packed 8-B stores.
// ---------------------------------------------------------------------------
__global__ __launch_bounds__(256) void k2_point(
    const void* __restrict__ xyz, const int* __restrict__ nei,
    const u16* __restrict__ fx,
    const void* __restrict__ W0, const void* __restrict__ g0, const void* __restrict__ b0,
    const void* __restrict__ W1, const void* __restrict__ g1, const void* __restrict__ b1,
    const void* __restrict__ W2, const void* __restrict__ g2, const void* __restrict__ b2,
    u16* __restrict__ nf16, float* __restrict__ locout, int n0, int n1)
{
  __shared__ float sW0[24], sB0[8], sW1[64], sB1[8], sW2[128], sB2[16];
  __shared__ int   sIdx[4][16];
  __shared__ float sLoc[4][48];
  __shared__ float sHa[4][128];
  __shared__ float sHb[4][128];
  alignas(16) __shared__ u16 sPT[4][16 * 24];   // [w][j*24 + k]  (wgt^T, bf16)
  alignas(16) __shared__ u16 sGFT[4][32 * 24];  // [w][c*24 + k]  (gf^T, bf16)

  bool bf = probe_bf16(g0);
  int tid = threadIdx.x;
  if (tid < 24) sW0[tid] = ldf(W0, tid, bf) * ldf(g0, tid & 7, bf);
  else if (tid < 32) sB0[tid - 24] = ldf(b0, tid - 24, bf);
  else if (tid < 96) sW1[tid - 32] = ldf(W1, tid - 32, bf) * ldf(g1, (tid - 32) & 7, bf);
  else if (tid < 104) sB1[tid - 96] = ldf(b1, tid - 96, bf);
  else if (tid < 232) sW2[tid - 104] = ldf(W2, tid - 104, bf) * ldf(g2, (tid - 104) & 15, bf);
  else if (tid < 248) sB2[tid - 232] = ldf(b2, tid - 232, bf);

  int w = tid >> 6, lane = tid & 63;
  int n = n0 + blockIdx.x * 4 + w;
  bool valid = n < n1;

  if (lane < 16) sIdx[w][lane] = valid ? nei[(size_t)n * 16 + lane] : 0;
  __syncthreads();

  if (lane < 48) {
    int k = lane / 3, d = lane - k * 3;
    float v = 0.f;
    if (valid) {
      int m = sIdx[w][k];
      v = ldf(xyz, (size_t)m * 3 + d, bf) - ldf(xyz, (size_t)n * 3 + d, bf);
      locout[(size_t)n * 48 + lane] = v;
    }
    sLoc[w][lane] = v;
  }

  // ---- gather fx rows (bf16) and scatter transposed into sGFT ----
  {
    int k = lane & 15, cg = lane >> 4;      // neighbor k, channel-group
    int m = sIdx[w][k];
    bf16x8 v = *reinterpret_cast<const bf16x8*>(fx + (size_t)m * 32 + cg * 8);
#pragma unroll
    for (int e = 0; e < 8; ++e)
      sGFT[w][(cg * 8 + e) * 24 + k] = (u16)v[e];
  }
  __syncthreads();

#pragma unroll
  for (int r = 0; r < 2; ++r) {
    int o = lane + r * 64;
    int k = o >> 3, j = o & 7;
    float a = sB0[j];
#pragma unroll
    for (int d = 0; d < 3; ++d) a += sLoc[w][k * 3 + d] * sW0[d * 8 + j];
    sHa[w][o] = fmaxf(a, 0.f);
  }
  __syncthreads();
#pragma unroll
  for (int r = 0; r < 2; ++r) {
    int o = lane + r * 64;
    int k = o >> 3, j = o & 7;
    float a = sB1[j];
#pragma unroll
    for (int d = 0; d < 8; ++d) a += sHa[w][k * 8 + d] * sW1[d * 8 + j];
    sHb[w][o] = fmaxf(a, 0.f);
  }
  __syncthreads();
#pragma unroll
  for (int r = 0; r < 4; ++r) {
    int o = lane + r * 64;
    int k = o >> 4, j = o & 15;
    float a = sB2[j];
#pragma unroll
    for (int d = 0; d < 8; ++d) a += sHb[w][k * 8 + d] * sW2[d * 16 + j];
    sPT[w][j * 24 + k] = f2bf(fmaxf(a, 0.f));   // transposed bf16
  }
  __syncthreads();

  // ---- einsum via MFMA: D[c][j] = sum_k gf^T[c][k] * wgt[k][j] ----
  {
    int kgrp = lane >> 4;       // 0..3 ; k = kgrp*8+e, only k<16 real
    int cb = lane & 15;
    bf16x8 a0 = (bf16x8){0,0,0,0,0,0,0,0};
    bf16x8 a1 = a0, b = a0;
    if (kgrp < 2) {
      a0 = *reinterpret_cast<const bf16x8*>(&sGFT[w][(cb)      * 24 + kgrp * 8]);
      a1 = *reinterpret_cast<const bf16x8*>(&sGFT[w][(16 + cb) * 24 + kgrp * 8]);
      b  = *reinterpret_cast<const bf16x8*>(&sPT [w][(cb)      * 24 + kgrp * 8]);
    }
    f32x4 acc0 = (f32x4){0.f, 0.f, 0.f, 0.f};
    f32x4 acc1 = acc0;
    acc0 = __builtin_amdgcn_mfma_f32_16x16x32_bf16(a0, b, acc0, 0, 0, 0);
    acc1 = __builtin_amdgcn_mfma_f32_16x16x32_bf16(a1, b, acc1, 0, 0, 0);
    if (valid) {
      // permuted store: position j*32 + c holds D[c][j]; j=cb (col),
      // c = tile*16 + rq*4 + v (row). One 8-B packed store per tile.
      u16* dst = nf16 + (size_t)(n - n0) * 512;
      int rq = lane >> 4;
      bf16x4 p0, p1;
#pragma unroll
      for (int v = 0; v < 4; ++v) { p0[v] = (short)f2bf(acc0[v]); p1[v] = (short)f2bf(acc1[v]); }
      *reinterpret_cast<bf16x4*>(dst + cb * 32 + rq * 4)      = p0;
      *reinterpret_cast<bf16x4*>(dst + cb * 32 + 16 + rq * 4) = p1;
    }
  }
}

// ---------------------------------------------------------------------------
// K3: MFMA bf16 GEMM  h[cnt,64] = relu(nf16[cnt,512] @ (W_lin*g) + b), bf16 out
// nf rows are PERMUTED (pos p = j*32+c holds flat index c*16+j); B-staging
// applies the same permutation to W_lin rows -> dot product exact.
// 256 thr = 4 waves; tile BM=128 x BN=64; full B staged once (64KB);
// A per 64-k slab (16KB); XOR-swizzled 16B chunks.
// ---------------------------------------------------------------------------
__global__ __launch_bounds__(256) void k3_gemm(
    const u16* __restrict__ nf, const void* __restrict__ WL,
    const void* __restrict__ gl, const void* __restrict__ bl,
    u16* __restrict__ h, int cnt)
{
  alignas(16) __shared__ u16 As[128 * 64];   // [row][kchunk swizzled]
  alignas(16) __shared__ u16 Bs[64 * 512];   // [col][kchunk swizzled]
  bool bf = probe_bf16(gl);
  int t = threadIdx.x;
  int lane = t & 63, w = t >> 6;
  int m0 = blockIdx.x * 128;

  // ---- stage all of B once (g-folded, bf16, swizzled, row-permuted) ----
  {
    int c = t & 63, kh = t >> 6;          // column, k-quarter
    float gc = ldf(gl, c, bf);
    int k0 = kh * 128;
#pragma unroll
    for (int q = 0; q < 16; ++q) {
      int kbase = k0 + q * 8;
      bf16x8 pk;
#pragma unroll
      for (int e = 0; e < 8; ++e) {
        int kp = kbase + e;               // permuted position
        int j = kp >> 5, cc = kp & 31;    // j in [0,16), cc in [0,32)
        int krow = cc * 16 + j;           // original W_lin row
        pk[e] = (short)f2bf(ldf(WL, (size_t)krow * 64 + c, bf) * gc);
      }
      int chunk = (kbase >> 3) ^ (c & 7);
      *reinterpret_cast<bf16x8*>(&Bs[c * 512 + chunk * 8]) = pk;
    }
  }

  f32x4 acc[2][4];
#pragma unroll
  for (int mi = 0; mi < 2; ++mi)
#pragma unroll
    for (int ni = 0; ni < 4; ++ni) acc[mi][ni] = (f32x4){0.f, 0.f, 0.f, 0.f};

  int mrow = t >> 1;            // staging row 0..127
  int half = t & 1;             // k-half of the 64-k slab

  for (int kb = 0; kb < 512; kb += 64) {
    __syncthreads();  // previous slab consumed (and Bs ready on first iter)
    // ---- stage A slab: rows m0..m0+127, k in [kb, kb+64) ----
    {
      int gm = m0 + mrow;
      if (gm >= cnt) gm = cnt - 1;        // clamp: safe reads, rows unused
      const u16* src = nf + (size_t)gm * 512 + kb + half * 32;
#pragma unroll
      for (int q = 0; q < 4; ++q) {
        bf16x8 v = *reinterpret_cast<const bf16x8*>(src + q * 8);
        int chunk = (half * 4 + q) ^ (mrow & 7);
        *reinterpret_cast<bf16x8*>(&As[mrow * 64 + chunk * 8]) = v;
      }
    }
    __syncthreads();
    // ---- compute: two K-steps of 32 ----
#pragma unroll
    for (int ks = 0; ks < 2; ++ks) {
      int qg = lane >> 4;                 // k-group 0..3
      bf16x8 a[2];
#pragma unroll
      for (int mi = 0; mi < 2; ++mi) {
        int row = w * 32 + mi * 16 + (lane & 15);
        int chunk = (ks * 4 + qg) ^ (row & 7);
        a[mi] = *reinterpret_cast<const bf16x8*>(&As[row * 64 + chunk * 8]);
      }
      bf16x8 bfr[4];
#pragma unroll
      for (int ni = 0; ni < 4; ++ni) {
        int col = ni * 16 + (lane & 15);
        int chunk = ((kb >> 3) + ks * 4 + qg) ^ (col & 7);
        bfr[ni] = *reinterpret_cast<const bf16x8*>(&Bs[col * 512 + chunk * 8]);
      }
#pragma unroll
      for (int mi = 0; mi < 2; ++mi)
#pragma unroll
        for (int ni = 0; ni < 4; ++ni)
          acc[mi][ni] = __builtin_amdgcn_mfma_f32_16x16x32_bf16(
              a[mi], bfr[ni], acc[mi][ni], 0, 0, 0);
    }
  }

  // ---- epilogue: C/D layout col=lane&15, row=(lane>>4)*4+reg; bf16 out ----
  int colb = lane & 15, rq = lane >> 4;
  float bias[4];
#pragma unroll
  for (int ni = 0; ni < 4; ++ni) bias[ni] = ldf(bl, ni * 16 + colb, bf);
#pragma unroll
  for (int mi = 0; mi < 2; ++mi) {
#pragma unroll
    for (int v = 0; v < 4; ++v) {
      int m = m0 + w * 32 + mi * 16 + rq * 4 + v;
      if (m < cnt) {
#pragma unroll
        for (int ni = 0; ni < 4; ++ni) {
          int j = ni * 16 + colb;
          h[(size_t)m * 64 + j] = f2bf(fmaxf(acc[mi][ni][v] + bias[ni], 0.f));
        }
      }
    }
  }
}

// ---------------------------------------------------------------------------
// K4: MFMA bf16 GEMM  out[cnt,128] = lrelu([h|feats] @ [[Wu2*g];[Wsc*g]] + b)
// BM=128 BN=128, K=128 staged entirely: As[row][128] 32KB (h | feats),
// Bs[col][128] 32KB (Wu2;Wsc g-folded). XOR-swizzled 16B chunks.
// 4 waves; per wave 2 m-frags x 8 n-frags x 4 K-steps = 64 MFMAs.
// ---------------------------------------------------------------------------
__global__ __launch_bounds__(256) void k4_gemm(
    const u16* __restrict__ hb, const void* __restrict__ feats,
    const void* __restrict__ Wu2, const void* __restrict__ gu2, const void* __restrict__ bu2,
    const void* __restrict__ Wsc, const void* __restrict__ gsc, const void* __restrict__ bsc,
    float* __restrict__ out, int n0c, int cnt)
{
  alignas(16) __shared__ u16 As[128 * 128];  // [row][kchunk swizzled]
  alignas(16) __shared__ u16 Bs[128 * 128];  // [col][kchunk swizzled]
  bool bf = probe_bf16(gu2);
  int t = threadIdx.x;
  int lane = t & 63, w = t >> 6;
  int m0 = blockIdx.x * 128;

  // ---- stage B: k<64 from Wu2*gu2, k>=64 from Wsc*gsc ----
  {
    int c = t & 127, kh = t >> 7;          // column, k-half
    const void* Wsel = kh ? Wsc : Wu2;
    const void* gsel = kh ? gsc : gu2;
    float gc = ldf(gsel, c, bf);
#pragma unroll
    for (int q = 0; q < 8; ++q) {
      bf16x8 pk;
#pragma unroll
      for (int e = 0; e < 8; ++e)
        pk[e] = (short)f2bf(ldf(Wsel, (size_t)(q * 8 + e) * 128 + c, bf) * gc);
      int chunk = (kh * 8 + q) ^ (c & 7);
      *reinterpret_cast<bf16x8*>(&Bs[c * 128 + chunk * 8]) = pk;
    }
  }
  // ---- stage A: row r, k<64 from hb (bf16), k>=64 from feats ----
  {
    int r = t >> 1, half = t & 1;
    int gm = m0 + r;
    if (gm >= cnt) gm = cnt - 1;           // clamp: safe reads, rows unused
    if (half == 0) {
      const u16* src = hb + (size_t)gm * 64;
#pragma unroll
      for (int q = 0; q < 8; ++q) {
        bf16x8 v = *reinterpret_cast<const bf16x8*>(src + q * 8);
        int chunk = q ^ (r & 7);
        *reinterpret_cast<bf16x8*>(&As[r * 128 + chunk * 8]) = v;
      }
    } else if (bf) {
      const u16* src = (const u16*)feats + (size_t)(n0c + gm) * 64;
#pragma unroll
      for (int q = 0; q < 8; ++q) {
        bf16x8 v = *reinterpret_cast<const bf16x8*>(src + q * 8);
        int chunk = (8 + q) ^ (r & 7);
        *reinterpret_cast<bf16x8*>(&As[r * 128 + chunk * 8]) = v;
      }
    } else {
      const float* src = (const float*)feats + (size_t)(n0c + gm) * 64;
#pragma unroll
      for (int q = 0; q < 8; ++q) {
        bf16x8 pk;
#pragma unroll
        for (int e = 0; e < 8; ++e) pk[e] = (short)f2bf(src[q * 8 + e]);
        int chunk = (8 + q) ^ (r & 7);
        *reinterpret_cast<bf16x8*>(&As[r * 128 + chunk * 8]) = pk;
      }
    }
  }
  __syncthreads();

  f32x4 acc[2][8];
#pragma unroll
  for (int mi = 0; mi < 2; ++mi)
#pragma unroll
    for (int ni = 0; ni < 8; ++ni) acc[mi][ni] = (f32x4){0.f, 0.f, 0.f, 0.f};

  int qg = lane >> 4;
#pragma unroll
  for (int ks = 0; ks < 4; ++ks) {
    bf16x8 a[2];
#pragma unroll
    for (int mi = 0; mi < 2; ++mi) {
      int row = w * 32 + mi * 16 + (lane & 15);
      int chunk = (ks * 4 + qg) ^ (row & 7);
      a[mi] = *reinterpret_cast<const bf16x8*>(&As[row * 128 + chunk * 8]);
    }
#pragma unroll
    for (int ni = 0; ni < 8; ++ni) {
      int col = ni * 16 + (lane & 15);
      int chunk = (ks * 4 + qg) ^ (col & 7);
      bf16x8 b = *reinterpret_cast<const bf16x8*>(&Bs[col * 128 + chunk * 8]);
      acc[0][ni] = __builtin_amdgcn_mfma_f32_16x16x32_bf16(a[0], b, acc[0][ni], 0, 0, 0);
      acc[1][ni] = __builtin_amdgcn_mfma_f32_16x16x32_bf16(a[1], b, acc[1][ni], 0, 0, 0);
    }
  }

  // ---- epilogue ----
  int colb = lane & 15, rq = lane >> 4;
  float bias[8];
#pragma unroll
  for (int ni = 0; ni < 8; ++ni) {
    int c = ni * 16 + colb;
    bias[ni] = ldf(bu2, c, bf) + ldf(bsc, c, bf);
  }
#pragma unroll
  for (int mi = 0; mi < 2; ++mi) {
#pragma unroll
    for (int v = 0; v < 4; ++v) {
      int m = m0 + w * 32 + mi * 16 + rq * 4 + v;
      if (m < cnt) {
        float* orow = out + (size_t)(n0c + m) * 128;
#pragma unroll
        for (int ni = 0; ni < 8; ++ni)
          orow[ni * 16 + colb] = lrelu(acc[mi][ni][v] + bias[ni]);
      }
    }
  }
}

extern "C" void kernel_launch(void* const* d_in, const int* in_sizes, int n_in,
                              void* d_out, int out_size, void* d_ws, size_t ws_size,
                              hipStream_t stream) {
  const void* xyz   = d_in[0];
  const void* feats = d_in[1];
  const int*  nei   = (const int*)d_in[2];
  const void* W_u1  = d_in[3];
  const void* g_u1  = d_in[4];
  const void* b_u1  = d_in[5];
  const void* W_wn0 = d_in[6];
  const void* g_wn0 = d_in[7];
  const void* b_wn0 = d_in[8];
  const void* W_wn1 = d_in[9];
  const void* g_wn1 = d_in[10];
  const void* b_wn1 = d_in[11];
  const void* W_wn2 = d_in[12];
  const void* g_wn2 = d_in[13];
  const void* b_wn2 = d_in[14];
  const void* W_lin = d_in[15];
  const void* g_lin = d_in[16];
  const void* b_lin = d_in[17];
  const void* W_u2  = d_in[18];
  const void* g_u2  = d_in[19];
  const void* b_u2  = d_in[20];
  const void* W_sc  = d_in[21];
  const void* g_sc  = d_in[22];
  const void* b_sc  = d_in[23];

  int Npts = in_sizes[0] / 3;

  float* out0 = (float*)d_out;                 // [N,128] f32
  float* out1 = out0 + (size_t)Npts * 128;     // [N,16,3] f32

  u16* fx = (u16*)d_ws;                        // [N,32] bf16
  size_t fx_bytes = (size_t)Npts * 32 * 2;
  size_t avail = (ws_size > fx_bytes) ? (ws_size - fx_bytes) : 0;
  size_t per_pt = (size_t)512 * 2 + (size_t)64 * 2;  // nf bf16 + h bf16 = 1152 B/pt
  long long cN = (long long)(avail / per_pt);
  if (cN < 1) cN = 1;
  if (cN > Npts) cN = Npts;
  int chunkN = (int)cN;

  u16* nf16 = fx + (size_t)Npts * 32;
  u16* hb   = nf16 + (size_t)chunkN * 512;

  k1_unary<<<(Npts + 127) / 128, 256, 0, stream>>>(feats, W_u1, g_u1, b_u1, fx, Npts);

  for (int n0 = 0; n0 < Npts; n0 += chunkN) {
    int n1 = n0 + chunkN;
    if (n1 > Npts) n1 = Npts;
    int cnt = n1 - n0;
    k2_point<<<(cnt + 3) / 4, 256, 0, stream>>>(
        xyz, nei, fx,
        W_wn0, g_wn0, b_wn0, W_wn1, g_wn1, b_wn1, W_wn2, g_wn2, b_wn2,
        nf16, out1, n0, n1);
    k3_gemm<<<(cnt + 127) / 128, 256, 0, stream>>>(nf16, W_lin, g_lin, b_lin, hb, cnt);
    k4_gemm<<<(cnt + 127) / 128, 256, 0, stream>>>(hb, feats, W_u2, g_u2, b_u2,
                                                   W_sc, g_sc, b_sc, out0, n0, cnt);
  }
}